// Round 11
// baseline (320.347 us; speedup 1.0000x reference)
//
#include <hip/hip_runtime.h>

// Problem constants (fixed by the reference)
#define T_    2048
#define N_    1024
#define MC_   512
#define KF_   20
#define M_    5
#define J_    (KF_ * MC_)      // 10240
#define NSEG  16
#define SEGLEN (T_ / NSEG)     // 128

typedef unsigned short u16;
typedef __attribute__((ext_vector_type(8))) __bf16 bf16v;          // MFMA A/B frag
typedef __attribute__((ext_vector_type(4))) float  f32x4;          // MFMA C/D frag
typedef __attribute__((ext_vector_type(8))) unsigned short u16x8;

__device__ inline u16 f2bf(float f) {                      // RNE f32 -> bf16
    unsigned u = __float_as_uint(f);
    u += 0x7fff + ((u >> 16) & 1);
    return (u16)(u >> 16);
}
__device__ inline float bf2f(u16 v) { return __uint_as_float((unsigned)v << 16); }

__device__ inline void gload16(const void* g, void* l) {   // 16B global -> LDS (lane*16 dest)
    __builtin_amdgcn_global_load_lds((const __attribute__((address_space(1))) void*)g,
                                     (__attribute__((address_space(3))) void*)l, 16, 0, 0);
}

// ---------------------------------------------------------------------------
// bf16 MFMA GEMM, TN form: C[m,n] = alpha * sum_k A[m,k]*B[n,k]
// EXACT r6/r10-proven inner structure (best of rounds 4-9): 128x128 tile,
// BK=64, 4 waves, double-buffered LDS, stage-next-early, one __syncthreads
// per K-step. LDS swizzle: 16B chunk ch (0..7) in each 128B row XORed with
// (row&7) on the GLOBAL SOURCE (dest linear, rule #21) and on ds_read;
// conflict-free (r5/r6: SQ_LDS_BANK_CONFLICT == 0).
// NEW (r11): strideB != 0 -> BATCH mode: bz indexes B (B += bz*strideB) and
// the Cp partial slot; full Kdim per block. strideB == 0 -> split-K as before.
// Cp: bf16 partials to Cp[bz]. else: +Add, write Cf (f32) and/or Cb (bf16).
// Block ids chunk-swizzled across 8 XCDs (bijective; total%8==0 always here).
// ---------------------------------------------------------------------------
__global__ __launch_bounds__(256) void gemm_tn(
    const u16* __restrict__ A, const u16* __restrict__ B,
    const float* __restrict__ Add, float* __restrict__ Cf,
    u16* __restrict__ Cb, u16* __restrict__ Cp,
    int Mdim, int Ndim, int Kdim, long strideB, float alpha)
{
    __shared__ u16 As[2][128 * 64];   // 16 KB per buffer
    __shared__ u16 Bs[2][128 * 64];

    // ---- XCD chunk swizzle (T1, bijective since total%8==0) ----
    const int gx = gridDim.x, gy = gridDim.y;
    const int total = gx * gy * gridDim.z;
    int lin = blockIdx.x + gx * (blockIdx.y + gy * blockIdx.z);
    lin = (lin & 7) * (total >> 3) + (lin >> 3);
    int bx, by, bz;
    if (gx <= gy) { bx = lin % gx; int r = lin / gx; by = r % gy; bz = r / gy; }
    else          { by = lin % gy; int r = lin / gy; bx = r % gx; bz = r / gx; }

    if (strideB) B += (size_t)bz * strideB;      // batch mode
    const int Kc   = strideB ? Kdim : (Kdim / gridDim.z);
    const int kbeg = strideB ? 0 : bz * Kc;

    const int tid = threadIdx.x;
    const int wv = tid >> 6, ln = tid & 63;
    const int wr = wv >> 1, wc = wv & 1;         // wave quadrant
    const int l15 = ln & 15, l4 = ln >> 4;
    const int m0 = by * 128, n0 = bx * 128;
    const int nt = Kc / 64;

    f32x4 acc[4][4] = {};

    // Staging: 128x64 tile = 1024 chunks of 16B; thread handles 4 chunks per
    // matrix: c_q = q*256 + tid. row = c>>3, ch = c&7; global source chunk is
    // ch ^ (row&7); LDS dest linear (wave-uniform base + lane*16).
    size_t arow[4], brow[4];
    int lbase[4];
    #pragma unroll
    for (int q = 0; q < 4; ++q) {
        const int c = q * 256 + tid;
        const int row = c >> 3, ch = c & 7;
        const int src = ((ch ^ (row & 7)) * 8);
        arow[q] = (size_t)(m0 + row) * Kdim + src;
        brow[q] = (size_t)(n0 + row) * Kdim + src;
        lbase[q] = (q * 256 + wv * 64) * 8;      // elements; wave-uniform
    }

    // Fragment-read swizzle: row&7 == l15&7 for every frag row.
    const int fsw = l15 & 7;

    // Prologue: stage tile 0
    #pragma unroll
    for (int q = 0; q < 4; ++q) {
        gload16(A + arow[q] + kbeg, &As[0][lbase[q]]);
        gload16(B + brow[q] + kbeg, &Bs[0][lbase[q]]);
    }
    __syncthreads();

    int cur = 0;
    for (int t = 0; t < nt; ++t) {
        if (t + 1 < nt) {          // stage next tile early (hidden under MFMA)
            const int kk = kbeg + (t + 1) * 64;
            #pragma unroll
            for (int q = 0; q < 4; ++q) {
                gload16(A + arow[q] + kk, &As[cur ^ 1][lbase[q]]);
                gload16(B + brow[q] + kk, &Bs[cur ^ 1][lbase[q]]);
            }
        }
        bf16v a[4][2], b[4][2];
        #pragma unroll
        for (int i = 0; i < 4; ++i)
            #pragma unroll
            for (int s = 0; s < 2; ++s) {
                const int ch = ((s * 4 + l4) ^ fsw) * 8;
                a[i][s] = *(const bf16v*)&As[cur][(wr * 64 + i * 16 + l15) * 64 + ch];
                b[i][s] = *(const bf16v*)&Bs[cur][(wc * 64 + i * 16 + l15) * 64 + ch];
            }
        #pragma unroll
        for (int s = 0; s < 2; ++s)
            #pragma unroll
            for (int i = 0; i < 4; ++i)
                #pragma unroll
                for (int j = 0; j < 4; ++j)
                    acc[i][j] = __builtin_amdgcn_mfma_f32_16x16x32_bf16(
                        a[i][s], b[j][s], acc[i][j], 0, 0, 0);
        __syncthreads();   // drains staging vmcnt; protects buf[cur] for next stage
        cur ^= 1;
    }

    // C/D layout: col = lane&15, row = (lane>>4)*4 + reg  [m89-verified]
    #pragma unroll
    for (int i = 0; i < 4; ++i)
        #pragma unroll
        for (int j = 0; j < 4; ++j)
            #pragma unroll
            for (int r = 0; r < 4; ++r) {
                const int gm = m0 + wr * 64 + i * 16 + l4 * 4 + r;
                const int gn = n0 + wc * 64 + j * 16 + l15;
                const size_t off = (size_t)gm * Ndim + gn;
                float v = alpha * acc[i][j][r];
                if (Cp) {
                    Cp[(size_t)bz * Mdim * Ndim + off] = f2bf(v);
                } else {
                    if (Add) v += Add[off];
                    if (Cf) Cf[off] = v;
                    if (Cb) Cb[off] = f2bf(v);
                }
            }
}

// Sum bf16 split-K partials (+f32 Add), write f32 and/or bf16. 8 elems/thread.
__global__ __launch_bounds__(256) void reduce_kb(
    const u16* __restrict__ Cp, int nz, int sz,
    const float* __restrict__ Add, float* __restrict__ Cf, u16* __restrict__ Cb)
{
    const size_t i = ((size_t)blockIdx.x * 256 + threadIdx.x) * 8;
    float s[8] = {};
    for (int z = 0; z < nz; ++z) {
        u16x8 v = *(const u16x8*)(Cp + (size_t)z * sz + i);
        #pragma unroll
        for (int k = 0; k < 8; ++k) s[k] += bf2f(v[k]);
    }
    if (Add) {
        float4 a0 = *(const float4*)(Add + i);
        float4 a1 = *(const float4*)(Add + i + 4);
        s[0] += a0.x; s[1] += a0.y; s[2] += a0.z; s[3] += a0.w;
        s[4] += a1.x; s[5] += a1.y; s[6] += a1.z; s[7] += a1.w;
    }
    if (Cf) {
        *(float4*)(Cf + i)     = make_float4(s[0], s[1], s[2], s[3]);
        *(float4*)(Cf + i + 4) = make_float4(s[4], s[5], s[6], s[7]);
    }
    if (Cb) {
        u16x8 o;
        #pragma unroll
        for (int k = 0; k < 8; ++k) o[k] = f2bf(s[k]);
        *(u16x8*)(Cb + i) = o;
    }
}

// phi-weighted batch reduce: Out[t,c] = sum_i phi[t,i] * Cp[i][t*C + c]
__global__ __launch_bounds__(256) void reduce_phi(
    const u16* __restrict__ Cp, const float* __restrict__ phi,
    int C, int sz, float* __restrict__ Out)
{
    const size_t idx = ((size_t)blockIdx.x * 256 + threadIdx.x) * 8;
    const int t = (int)(idx / C);
    float s[8] = {};
    #pragma unroll 4
    for (int i = 0; i < KF_; ++i) {
        const float ph = phi[t * KF_ + i];
        u16x8 v = *(const u16x8*)(Cp + (size_t)i * sz + idx);
        #pragma unroll
        for (int k = 0; k < 8; ++k) s[k] += ph * bf2f(v[k]);
    }
    *(float4*)(Out + idx)     = make_float4(s[0], s[1], s[2], s[3]);
    *(float4*)(Out + idx + 4) = make_float4(s[4], s[5], s[6], s[7]);
}

// Column-wise 3-pass strict prefix over [T_, C] f32
__global__ __launch_bounds__(256) void scan2S(const float* __restrict__ W, int C,
                                              float* __restrict__ S2)
{
    const int c = blockIdx.x * 256 + threadIdx.x;
    const int t0 = blockIdx.y * SEGLEN;
    float a = 0.f;
    for (int t = t0; t < t0 + SEGLEN; ++t) a += W[(size_t)t * C + c];
    S2[(size_t)blockIdx.y * C + c] = a;
}

__global__ __launch_bounds__(256) void scan2B(const float* __restrict__ S2, int C,
                                              float* __restrict__ O2)
{
    const int c = blockIdx.x * 256 + threadIdx.x;
    float off = 0.f;
    #pragma unroll
    for (int s = 0; s < NSEG; ++s) {
        O2[(size_t)s * C + c] = off;
        off += S2[(size_t)s * C + c];
    }
}

// OutB[t,c] = bf16( (Add? Add[t,c]:0) + sum_{s<t} W[s,c] )
__global__ __launch_bounds__(256) void scan2C(const float* __restrict__ W,
                                              const float* __restrict__ O2,
                                              const float* __restrict__ Add, int C,
                                              u16* __restrict__ OutB)
{
    const int c = blockIdx.x * 256 + threadIdx.x;
    const int t0 = blockIdx.y * SEGLEN;
    float acc = O2[(size_t)blockIdx.y * C + c];
    for (int t = t0; t < t0 + SEGLEN; ++t) {
        float v = acc + (Add ? Add[(size_t)t * C + c] : 0.f);
        OutB[(size_t)t * C + c] = f2bf(v);
        acc += W[(size_t)t * C + c];
    }
}

// fp32 -> bf16 cast (n4 = n/4 float4 groups)
__global__ __launch_bounds__(256) void cast_bf(const float* __restrict__ in,
                                               u16* __restrict__ out, int n4)
{
    const int i = blockIdx.x * 256 + threadIdx.x;
    if (i >= n4) return;
    float4 v = *(const float4*)(in + (size_t)i * 4);
    ushort4 o; o.x = f2bf(v.x); o.y = f2bf(v.y); o.z = f2bf(v.z); o.w = f2bf(v.w);
    *(ushort4*)(out + (size_t)i * 4) = o;
}

// EstuB[(i*1024 + n)*512 + c] = Estu[(i*512 + c)*1024 + n], bf16 (per-i transpose)
__global__ __launch_bounds__(256) void transpose_estub(const float* __restrict__ in,
                                                       u16* __restrict__ out)
{
    __shared__ float tile[32][33];
    const int j0 = blockIdx.x * 32, n0 = blockIdx.y * 32;   // j0 never straddles i
    const int tx = threadIdx.x & 31, ty = threadIdx.x >> 5;
    #pragma unroll
    for (int r = 0; r < 4; ++r)
        tile[ty + r * 8][tx] = in[(size_t)(j0 + ty + r * 8) * N_ + n0 + tx];
    __syncthreads();
    const int i = j0 >> 9, cbase = j0 & 511;
    #pragma unroll
    for (int r = 0; r < 4; ++r)
        out[((size_t)i * N_ + n0 + ty + r * 8) * MC_ + cbase + tx] =
            f2bf(tile[tx][ty + r * 8]);
}

// EbT[(c*5+ii)][n] = E[c][n][ii]  bf16  (B-operand for the ywE GEMM)
__global__ __launch_bounds__(256) void build_EbT(const float* __restrict__ E,
                                                 u16* __restrict__ EbT)
{
    const int c = blockIdx.x;
    for (int n = threadIdx.x; n < N_; n += 256) {
        const float* ep = E + (size_t)c * (N_ * M_) + (size_t)n * M_;
        #pragma unroll
        for (int ii = 0; ii < M_; ++ii)
            EbT[(size_t)(c * M_ + ii) * N_ + n] = f2bf(ep[ii]);
    }
}

// D[t,c] = bias[c] + sum_i ywE[t-4+i][c*5+i]; writes D f32 + U0 bf16
__global__ __launch_bounds__(256) void build_D(const float* __restrict__ ywE,
                                               const float* __restrict__ bias,
                                               float* __restrict__ D,
                                               u16* __restrict__ Ub0)
{
    const int idx = blockIdx.x * 256 + threadIdx.x;
    const int t = idx >> 9, c = idx & 511;
    float v = bias[c];
    #pragma unroll
    for (int ii = 0; ii < M_; ++ii) {
        int ts = t - (M_ - 1) + ii;
        if (ts >= 0) v += ywE[(size_t)ts * (MC_ * M_) + c * M_ + ii];
    }
    D[idx] = v;
    Ub0[idx] = f2bf(v);
}

// losses[t] = dot(Xb[t],Y[t]) + dot(Ub[t],Z[t])  (bf16 X/U, f32 Y/Z)
__global__ __launch_bounds__(256) void rowdot_b(
    const u16* __restrict__ Xb, const float* __restrict__ Y,
    const u16* __restrict__ Ub, const float* __restrict__ Z,
    float* __restrict__ out)
{
    const int t = blockIdx.x;
    float s = 0.f;
    for (int n = threadIdx.x; n < N_; n += 256)
        s += bf2f(Xb[(size_t)t * N_ + n]) * Y[(size_t)t * N_ + n];
    for (int c = threadIdx.x; c < MC_; c += 256)
        s += bf2f(Ub[(size_t)t * MC_ + c]) * Z[(size_t)t * MC_ + c];
    __shared__ float red[256];
    red[threadIdx.x] = s;
    __syncthreads();
    for (int off = 128; off > 0; off >>= 1) {
        if (threadIdx.x < off) red[threadIdx.x] += red[threadIdx.x + off];
        __syncthreads();
    }
    if (threadIdx.x == 0) out[t] = red[0];
}

// ---------------------------------------------------------------------------
extern "C" void kernel_launch(void* const* d_in, const int* in_sizes, int n_in,
                              void* d_out, int out_size, void* d_ws, size_t ws_size,
                              hipStream_t stream)
{
    const float* Qm   = (const float*)d_in[2];
    const float* Rm   = (const float*)d_in[3];
    const float* Km   = (const float*)d_in[4];
    const float* Em   = (const float*)d_in[5];
    const float* bias = (const float*)d_in[6];
    const float* Estu = (const float*)d_in[7];   // [J_, N_]
    const float* phi  = (const float*)d_in[8];   // [T, KF]
    const float* w    = (const float*)d_in[9];   // [T, N]
    float* out = (float*)d_out;

    // ---- workspace: 84 MB phase-overlaid region P + ~43 MB persistent = 127.6 MB
    char* w8 = (char*)d_ws;
    size_t off = 0;
    auto alloc = [&](size_t bytes) -> void* {
        void* p = w8 + off; off += (bytes + 255) & ~(size_t)255; return p;
    };
    char*  P     = (char*) alloc(83886080);              // 84 MB overlay region
    u16*   EstuB = (u16*)  alloc((size_t)KF_ * N_ * MC_ * 2);  // 21 MB
    float* D     = (float*)alloc((size_t)T_ * MC_ * 4);
    u16*   Ub0   = (u16*)  alloc((size_t)T_ * MC_ * 2);
    u16*   Ub    = (u16*)  alloc((size_t)T_ * MC_ * 2);
    float* V     = (float*)alloc((size_t)T_ * N_ * 4);   // 8 MB (W aliases first 4)
    u16*   Xb    = (u16*)  alloc((size_t)T_ * N_ * 2);
    u16*   Qb    = (u16*)  alloc((size_t)N_ * N_ * 2);
    u16*   Rb    = (u16*)  alloc((size_t)MC_ * MC_ * 2);
    float* S2    = (float*)alloc((size_t)NSEG * N_ * 4);
    float* O2    = (float*)alloc((size_t)NSEG * N_ * 4);
    float* W     = V;                                    // [T, MC] f32 alias

    // P-region overlays:
    // phase 1: Fb2 | Eb | EbT | Kb | Wb | CpYwe | ywE      (exactly 84 MB)
    // phase 2: Fb2 | CpNeu (42 MB @10.5M; Eb..CpYwe dead)
    // phase 3: CpX (84 MB; Fb2 dead after Neumann GEMM)
    // phase 4: CpY | Yf | CpZ | Zf
    u16*   Fb2   = (u16*)  P;                            // 10.5 MB [J, MC] bf16
    u16*   Eb    = (u16*)  (P + 10485760);               // 21 MB Estu bf16 [J, N]
    u16*   EbT   = (u16*)  (P + 31457280);               //  5.2 MB
    u16*   Kb    = (u16*)  (P + 36700160);               //  1 MB
    u16*   Wb    = (u16*)  (P + 37748736);               //  4.2 MB
    u16*   CpYwe = (u16*)  (P + 41943040);               // 21 MB
    float* ywE   = (float*)(P + 62914560);               // 21 MB
    u16*   CpNeu = (u16*)  (P + 10485760);               // 42 MB
    u16*   CpX   = (u16*)  P;                            // 84 MB
    u16*   CpY   = (u16*)  P;                            // 16.8 MB
    float* Yf    = (float*)(P + 16777216);               //  8 MB
    u16*   CpZ   = (u16*)  (P + 25165824);               //  8.4 MB
    float* Zf    = (float*)(P + 33554432);               //  4 MB

    dim3 blk(256);

    // Phase 1: casts + operand builders
    cast_bf<<<dim3(MC_ * N_ / 1024), blk, 0, stream>>>(Km, Kb, MC_ * N_ / 4);
    cast_bf<<<dim3(N_ * N_ / 1024), blk, 0, stream>>>(Qm, Qb, N_ * N_ / 4);
    cast_bf<<<dim3(MC_ * MC_ / 1024), blk, 0, stream>>>(Rm, Rb, MC_ * MC_ / 4);
    cast_bf<<<dim3(T_ * N_ / 1024), blk, 0, stream>>>(w, Wb, T_ * N_ / 4);
    cast_bf<<<dim3(J_ * N_ / 1024), blk, 0, stream>>>(Estu, Eb, J_ * N_ / 4);
    build_EbT<<<dim3(MC_), blk, 0, stream>>>(Em, EbT);
    transpose_estub<<<dim3(J_ / 32, N_ / 32), blk, 0, stream>>>(Estu, EstuB);

    // F2[(i,c'),c] = -sum_n K[c',n]*Estu[(i,c),n]  — batched (z=i), 320 blocks
    gemm_tn<<<dim3(4, 4, KF_), blk, 0, stream>>>(
        Kb, Eb, nullptr, nullptr, nullptr, Fb2, MC_, MC_, N_, (long)MC_ * N_, -1.0f);

    // ywE (split-K z=2; 640 blocks) -> D, U0
    gemm_tn<<<dim3((MC_ * M_) / 128, T_ / 128, 2), blk, 0, stream>>>(
        Wb, EbT, nullptr, nullptr, nullptr, CpYwe, T_, MC_ * M_, N_, 0, 1.0f);
    reduce_kb<<<dim3(T_ * (MC_ * M_) / 2048), blk, 0, stream>>>(
        CpYwe, 2, T_ * (MC_ * M_), nullptr, ywE, nullptr);
    build_D<<<dim3(T_ * MC_ / 256), blk, 0, stream>>>(ywE, bias, D, Ub0);

    // Phase 2 — Neumann (NIT=1 via prefix-commute):
    // partial_i[t,c'] = (F_i u0_t)[c'];  W[t] = sum_i phi[t,i]*partial_i[t];
    // U1[t] = D[t] + sum_{s<t} W[s]   (batched GEMM z=20, 1280 blocks)
    gemm_tn<<<dim3(4, 16, KF_), blk, 0, stream>>>(
        Ub0, Fb2, nullptr, nullptr, nullptr, CpNeu, T_, MC_, MC_, (long)MC_ * MC_, 1.0f);
    reduce_phi<<<dim3(T_ * MC_ / 2048), blk, 0, stream>>>(
        CpNeu, phi, MC_, T_ * MC_, W);
    scan2S<<<dim3(MC_ / 256, NSEG), blk, 0, stream>>>(W, MC_, S2);
    scan2B<<<dim3(MC_ / 256), blk, 0, stream>>>(S2, MC_, O2);
    scan2C<<<dim3(MC_ / 256, NSEG), blk, 0, stream>>>(W, O2, D, MC_, Ub);

    // Phase 3 — X: partial_i[t,n] = (Estu_i^T u1_t)[n]; V = phi-reduce;
    // X[t] = sum_{s<t} V[s]   (batched GEMM z=20, 2560 blocks)
    gemm_tn<<<dim3(8, 16, KF_), blk, 0, stream>>>(
        Ub, EstuB, nullptr, nullptr, nullptr, CpX, T_, N_, MC_, (long)N_ * MC_, 1.0f);
    reduce_phi<<<dim3(T_ * N_ / 2048), blk, 0, stream>>>(
        CpX, phi, N_, T_ * N_, V);
    scan2S<<<dim3(N_ / 256, NSEG), blk, 0, stream>>>(V, N_, S2);
    scan2B<<<dim3(N_ / 256), blk, 0, stream>>>(S2, N_, O2);
    scan2C<<<dim3(N_ / 256, NSEG), blk, 0, stream>>>(V, O2, nullptr, N_, Xb);

    // Phase 4 — Y = X@Q (split-K z=4), Z = U@R (split-K z=4), losses
    gemm_tn<<<dim3(N_ / 128, T_ / 128, 4), blk, 0, stream>>>(
        Xb, Qb, nullptr, nullptr, nullptr, CpY, T_, N_, N_, 0, 1.0f);
    reduce_kb<<<dim3(T_ * N_ / 2048), blk, 0, stream>>>(
        CpY, 4, T_ * N_, nullptr, Yf, nullptr);
    gemm_tn<<<dim3(MC_ / 128, T_ / 128, 4), blk, 0, stream>>>(
        Ub, Rb, nullptr, nullptr, nullptr, CpZ, T_, MC_, MC_, 0, 1.0f);
    reduce_kb<<<dim3(T_ * MC_ / 2048), blk, 0, stream>>>(
        CpZ, 4, T_ * MC_, nullptr, Zf, nullptr);
    rowdot_b<<<dim3(T_), blk, 0, stream>>>(Xb, Yf, Ub, Zf, out);
}

// Round 12
// 279.165 us; speedup vs baseline: 1.1475x; 1.1475x over previous
//
#include <hip/hip_runtime.h>

// Problem constants (fixed by the reference)
#define T_    2048
#define N_    1024
#define MC_   512
#define KF_   20
#define M_    5
#define J_    (KF_ * MC_)      // 10240
#define NSEG2 64
#define SEGLEN2 (T_ / NSEG2)   // 32

typedef unsigned short u16;
typedef __attribute__((ext_vector_type(8))) __bf16 bf16v;          // MFMA A/B frag
typedef __attribute__((ext_vector_type(4))) float  f32x4;          // MFMA C/D frag
typedef __attribute__((ext_vector_type(8))) unsigned short u16x8;

__device__ inline u16 f2bf(float f) {                      // RNE f32 -> bf16
    unsigned u = __float_as_uint(f);
    u += 0x7fff + ((u >> 16) & 1);
    return (u16)(u >> 16);
}
__device__ inline float bf2f(u16 v) { return __uint_as_float((unsigned)v << 16); }

__device__ inline void gload16(const void* g, void* l) {   // 16B global -> LDS (lane*16 dest)
    __builtin_amdgcn_global_load_lds((const __attribute__((address_space(1))) void*)g,
                                     (__attribute__((address_space(3))) void*)l, 16, 0, 0);
}

// ---------------------------------------------------------------------------
// bf16 MFMA GEMM, TN form (r6/r10-proven core): 128x128 tile, BK=64, 4 waves,
// double-buffered LDS, stage-next-early, one __syncthreads per K-step.
// LDS swizzle: 16B chunk ch (0..7) in each 128B row XORed with (row&7) on the
// GLOBAL SOURCE (dest linear, rule #21) and on ds_read; conflict-free.
// strideB != 0 -> BATCH mode (bz indexes B and the Cp slot, full Kdim).
// strideB == 0 -> split-K over grid.z. Cp: bf16 per-bz output. else +Add,
// write Cf (f32) / Cb (bf16). XCD chunk-swizzled block ids (total%8==0).
// ---------------------------------------------------------------------------
__global__ __launch_bounds__(256) void gemm_tn(
    const u16* __restrict__ A, const u16* __restrict__ B,
    const float* __restrict__ Add, float* __restrict__ Cf,
    u16* __restrict__ Cb, u16* __restrict__ Cp,
    int Mdim, int Ndim, int Kdim, long strideB, float alpha)
{
    __shared__ u16 As[2][128 * 64];
    __shared__ u16 Bs[2][128 * 64];

    const int gx = gridDim.x, gy = gridDim.y;
    const int total = gx * gy * gridDim.z;
    int lin = blockIdx.x + gx * (blockIdx.y + gy * blockIdx.z);
    lin = (lin & 7) * (total >> 3) + (lin >> 3);
    int bx, by, bz;
    if (gx <= gy) { bx = lin % gx; int r = lin / gx; by = r % gy; bz = r / gy; }
    else          { by = lin % gy; int r = lin / gy; bx = r % gx; bz = r / gx; }

    if (strideB) B += (size_t)bz * strideB;
    const int Kc   = strideB ? Kdim : (Kdim / gridDim.z);
    const int kbeg = strideB ? 0 : bz * Kc;

    const int tid = threadIdx.x;
    const int wv = tid >> 6, ln = tid & 63;
    const int wr = wv >> 1, wc = wv & 1;
    const int l15 = ln & 15, l4 = ln >> 4;
    const int m0 = by * 128, n0 = bx * 128;
    const int nt = Kc / 64;

    f32x4 acc[4][4] = {};

    size_t arow[4], brow[4];
    int lbase[4];
    #pragma unroll
    for (int q = 0; q < 4; ++q) {
        const int c = q * 256 + tid;
        const int row = c >> 3, ch = c & 7;
        const int src = ((ch ^ (row & 7)) * 8);
        arow[q] = (size_t)(m0 + row) * Kdim + src;
        brow[q] = (size_t)(n0 + row) * Kdim + src;
        lbase[q] = (q * 256 + wv * 64) * 8;
    }
    const int fsw = l15 & 7;

    #pragma unroll
    for (int q = 0; q < 4; ++q) {
        gload16(A + arow[q] + kbeg, &As[0][lbase[q]]);
        gload16(B + brow[q] + kbeg, &Bs[0][lbase[q]]);
    }
    __syncthreads();

    int cur = 0;
    for (int t = 0; t < nt; ++t) {
        if (t + 1 < nt) {
            const int kk = kbeg + (t + 1) * 64;
            #pragma unroll
            for (int q = 0; q < 4; ++q) {
                gload16(A + arow[q] + kk, &As[cur ^ 1][lbase[q]]);
                gload16(B + brow[q] + kk, &Bs[cur ^ 1][lbase[q]]);
            }
        }
        bf16v a[4][2], b[4][2];
        #pragma unroll
        for (int i = 0; i < 4; ++i)
            #pragma unroll
            for (int s = 0; s < 2; ++s) {
                const int ch = ((s * 4 + l4) ^ fsw) * 8;
                a[i][s] = *(const bf16v*)&As[cur][(wr * 64 + i * 16 + l15) * 64 + ch];
                b[i][s] = *(const bf16v*)&Bs[cur][(wc * 64 + i * 16 + l15) * 64 + ch];
            }
        #pragma unroll
        for (int s = 0; s < 2; ++s)
            #pragma unroll
            for (int i = 0; i < 4; ++i)
                #pragma unroll
                for (int j = 0; j < 4; ++j)
                    acc[i][j] = __builtin_amdgcn_mfma_f32_16x16x32_bf16(
                        a[i][s], b[j][s], acc[i][j], 0, 0, 0);
        __syncthreads();
        cur ^= 1;
    }

    #pragma unroll
    for (int i = 0; i < 4; ++i)
        #pragma unroll
        for (int j = 0; j < 4; ++j)
            #pragma unroll
            for (int r = 0; r < 4; ++r) {
                const int gm = m0 + wr * 64 + i * 16 + l4 * 4 + r;
                const int gn = n0 + wc * 64 + j * 16 + l15;
                const size_t off = (size_t)gm * Ndim + gn;
                float v = alpha * acc[i][j][r];
                if (Cp) {
                    Cp[(size_t)bz * Mdim * Ndim + off] = f2bf(v);
                } else {
                    if (Add) v += Add[off];
                    if (Cf) Cf[off] = v;
                    if (Cb) Cb[off] = f2bf(v);
                }
            }
}

// ---------------------------------------------------------------------------
// gemm_phi (r12): batched TN GEMM with phi-scale FUSED in the epilogue.
// Kdim MUST be 512 (8 K-steps). bz = batch GROUP of NB consecutive i; block
// loops its NB batches (staging totals unchanged; A re-staged per i from L2),
// accumulating accF += phi[row, i] * acc after each batch's K-loop.
// Partials: Cp[bz][t*Ndim+n] bf16 (one per group, not per batch).
// Same r6-proven inner loop, swizzle, and XCD block swizzle.
// ---------------------------------------------------------------------------
__global__ __launch_bounds__(256, 2) void gemm_phi(
    const u16* __restrict__ A, const u16* __restrict__ B,
    const float* __restrict__ phi_, u16* __restrict__ Cp,
    int Mdim, int Ndim, long strideB, int NB)
{
    __shared__ u16 As[2][128 * 64];
    __shared__ u16 Bs[2][128 * 64];
    const int Kdim = 512;

    const int gx = gridDim.x, gy = gridDim.y;
    const int total = gx * gy * gridDim.z;
    int lin = blockIdx.x + gx * (blockIdx.y + gy * blockIdx.z);
    lin = (lin & 7) * (total >> 3) + (lin >> 3);
    int bx, by, bz;
    if (gx <= gy) { bx = lin % gx; int r = lin / gx; by = r % gy; bz = r / gy; }
    else          { by = lin % gy; int r = lin / gy; bx = r % gx; bz = r / gx; }

    const int tid = threadIdx.x;
    const int wv = tid >> 6, ln = tid & 63;
    const int wr = wv >> 1, wc = wv & 1;
    const int l15 = ln & 15, l4 = ln >> 4;
    const int m0 = by * 128, n0 = bx * 128;

    f32x4 acc[4][4] = {};
    f32x4 accF[4][4] = {};

    size_t arow[4], brow[4];
    int lbase[4];
    #pragma unroll
    for (int q = 0; q < 4; ++q) {
        const int c = q * 256 + tid;
        const int row = c >> 3, ch = c & 7;
        const int src = ((ch ^ (row & 7)) * 8);
        arow[q] = (size_t)(m0 + row) * Kdim + src;
        brow[q] = (size_t)(n0 + row) * Kdim + src;
        lbase[q] = (q * 256 + wv * 64) * 8;
    }
    const int fsw = l15 & 7;
    const int NT = NB * 8;

    auto stage = [&](int u, int bb) {
        const int qb = u >> 3, tt = u & 7;
        const u16* Bq = B + (size_t)(bz * NB + qb) * strideB;
        const int kk = tt * 64;
        #pragma unroll
        for (int q = 0; q < 4; ++q) {
            gload16(A + arow[q] + kk, &As[bb][lbase[q]]);
            gload16(Bq + brow[q] + kk, &Bs[bb][lbase[q]]);
        }
    };

    stage(0, 0);
    __syncthreads();

    int cur = 0;
    for (int u = 0; u < NT; ++u) {
        if (u + 1 < NT) stage(u + 1, cur ^ 1);
        bf16v a[4][2], b[4][2];
        #pragma unroll
        for (int i = 0; i < 4; ++i)
            #pragma unroll
            for (int s = 0; s < 2; ++s) {
                const int ch = ((s * 4 + l4) ^ fsw) * 8;
                a[i][s] = *(const bf16v*)&As[cur][(wr * 64 + i * 16 + l15) * 64 + ch];
                b[i][s] = *(const bf16v*)&Bs[cur][(wc * 64 + i * 16 + l15) * 64 + ch];
            }
        #pragma unroll
        for (int s = 0; s < 2; ++s)
            #pragma unroll
            for (int i = 0; i < 4; ++i)
                #pragma unroll
                for (int j = 0; j < 4; ++j)
                    acc[i][j] = __builtin_amdgcn_mfma_f32_16x16x32_bf16(
                        a[i][s], b[j][s], acc[i][j], 0, 0, 0);
        if ((u & 7) == 7) {                      // end of batch i: fold phi
            const int ig = bz * NB + (u >> 3);
            float ph[4][4];
            #pragma unroll
            for (int i = 0; i < 4; ++i)
                #pragma unroll
                for (int r = 0; r < 4; ++r)
                    ph[i][r] = phi_[(size_t)(m0 + wr * 64 + i * 16 + l4 * 4 + r) * KF_ + ig];
            #pragma unroll
            for (int i = 0; i < 4; ++i)
                #pragma unroll
                for (int j = 0; j < 4; ++j) {
                    #pragma unroll
                    for (int r = 0; r < 4; ++r)
                        accF[i][j][r] += ph[i][r] * acc[i][j][r];
                    acc[i][j] = (f32x4){0.f, 0.f, 0.f, 0.f};
                }
        }
        __syncthreads();
        cur ^= 1;
    }

    #pragma unroll
    for (int i = 0; i < 4; ++i)
        #pragma unroll
        for (int j = 0; j < 4; ++j)
            #pragma unroll
            for (int r = 0; r < 4; ++r) {
                const int gm = m0 + wr * 64 + i * 16 + l4 * 4 + r;
                const int gn = n0 + wc * 64 + j * 16 + l15;
                Cp[(size_t)bz * Mdim * Ndim + (size_t)gm * Ndim + gn] = f2bf(accF[i][j][r]);
            }
}

// All five f32->bf16 casts in one kernel (range-dispatched on float4 index)
__global__ __launch_bounds__(256) void cast_all(
    const float* __restrict__ Km, const float* __restrict__ Qm,
    const float* __restrict__ Rm, const float* __restrict__ w,
    const float* __restrict__ Estu,
    u16* __restrict__ Kb, u16* __restrict__ Qb, u16* __restrict__ Rb,
    u16* __restrict__ Wb, u16* __restrict__ Eb)
{
    const int g = blockIdx.x * 256 + threadIdx.x;   // float4 index, total 3604480
    const float* src; u16* dst; int base;
    if      (g <  131072) { src = Km;   dst = Kb; base = 0; }
    else if (g <  393216) { src = Qm;   dst = Qb; base = 131072; }
    else if (g <  458752) { src = Rm;   dst = Rb; base = 393216; }
    else if (g <  983040) { src = w;    dst = Wb; base = 458752; }
    else                  { src = Estu; dst = Eb; base = 983040; }
    const int i = g - base;
    float4 v = *(const float4*)(src + (size_t)i * 4);
    ushort4 o; o.x = f2bf(v.x); o.y = f2bf(v.y); o.z = f2bf(v.z); o.w = f2bf(v.w);
    *(ushort4*)(dst + (size_t)i * 4) = o;
}

// EstuB[(i*1024 + n)*512 + c] = Estu[(i*512 + c)*1024 + n], bf16
__global__ __launch_bounds__(256) void transpose_estub(const float* __restrict__ in,
                                                       u16* __restrict__ out)
{
    __shared__ float tile[32][33];
    const int j0 = blockIdx.x * 32, n0 = blockIdx.y * 32;
    const int tx = threadIdx.x & 31, ty = threadIdx.x >> 5;
    #pragma unroll
    for (int r = 0; r < 4; ++r)
        tile[ty + r * 8][tx] = in[(size_t)(j0 + ty + r * 8) * N_ + n0 + tx];
    __syncthreads();
    const int i = j0 >> 9, cbase = j0 & 511;
    #pragma unroll
    for (int r = 0; r < 4; ++r)
        out[((size_t)i * N_ + n0 + ty + r * 8) * MC_ + cbase + tx] =
            f2bf(tile[tx][ty + r * 8]);
}

// EbT[(c*5+ii)][n] = E[c][n][ii]  bf16
__global__ __launch_bounds__(256) void build_EbT(const float* __restrict__ E,
                                                 u16* __restrict__ EbT)
{
    const int c = blockIdx.x;
    for (int n = threadIdx.x; n < N_; n += 256) {
        const float* ep = E + (size_t)c * (N_ * M_) + (size_t)n * M_;
        #pragma unroll
        for (int ii = 0; ii < M_; ++ii)
            EbT[(size_t)(c * M_ + ii) * N_ + n] = f2bf(ep[ii]);
    }
}

// D[t,c] = bias[c] + sum_z sum_ii CpYwe[z][(t-4+ii)*2560 + c*5+ii]  (fused reduce)
__global__ __launch_bounds__(256) void build_D2(const u16* __restrict__ Cp,
                                                const float* __restrict__ bias,
                                                float* __restrict__ D,
                                                u16* __restrict__ Ub0)
{
    const int idx = blockIdx.x * 256 + threadIdx.x;
    const int t = idx >> 9, c = idx & 511;
    float v = bias[c];
    #pragma unroll
    for (int ii = 0; ii < M_; ++ii) {
        const int ts = t - (M_ - 1) + ii;
        if (ts >= 0) {
            v += bf2f(Cp[(size_t)ts * (MC_ * M_) + c * M_ + ii]);
            v += bf2f(Cp[(size_t)T_ * (MC_ * M_) + (size_t)ts * (MC_ * M_) + c * M_ + ii]);
        }
    }
    D[idx] = v;
    Ub0[idx] = f2bf(v);
}

// Neumann: W[t,c] = sum_i phi[t,i]*Cp[i][t*MC+c], plus segment sums S2
__global__ __launch_bounds__(256) void phired_scanS(
    const u16* __restrict__ Cp, const float* __restrict__ phi_,
    float* __restrict__ W, float* __restrict__ S2)
{
    const int c = blockIdx.x * 256 + threadIdx.x;
    const int t0 = blockIdx.y * SEGLEN2;
    float a = 0.f;
    for (int t = t0; t < t0 + SEGLEN2; ++t) {
        float s = 0.f;
        #pragma unroll 4
        for (int i = 0; i < KF_; ++i)
            s += phi_[t * KF_ + i] * bf2f(Cp[(size_t)i * (T_ * MC_) + (size_t)t * MC_ + c]);
        W[(size_t)t * MC_ + c] = s;
        a += s;
    }
    S2[(size_t)blockIdx.y * MC_ + c] = a;
}

// X: V[t,n] = sum_z Cp[z][t*N+n], plus segment sums S2
__global__ __launch_bounds__(256) void sumred_scanS(
    const u16* __restrict__ Cp, float* __restrict__ V, float* __restrict__ S2)
{
    const int n = blockIdx.x * 256 + threadIdx.x;
    const int t0 = blockIdx.y * SEGLEN2;
    float a = 0.f;
    for (int t = t0; t < t0 + SEGLEN2; ++t) {
        float s = 0.f;
        #pragma unroll
        for (int z = 0; z < 4; ++z)
            s += bf2f(Cp[(size_t)z * (T_ * N_) + (size_t)t * N_ + n]);
        V[(size_t)t * N_ + n] = s;
        a += s;
    }
    S2[(size_t)blockIdx.y * N_ + n] = a;
}

// Exclusive scan of NSEG2 segment sums per column
__global__ __launch_bounds__(256) void scan2B(const float* __restrict__ S2, int C,
                                              float* __restrict__ O2)
{
    const int c = blockIdx.x * 256 + threadIdx.x;
    float off = 0.f;
    #pragma unroll
    for (int s = 0; s < NSEG2; ++s) {
        O2[(size_t)s * C + c] = off;
        off += S2[(size_t)s * C + c];
    }
}

// OutB[t,c] = bf16( (Add? Add[t,c]:0) + strict-prefix(W)[t,c] )
__global__ __launch_bounds__(256) void scan2C(const float* __restrict__ W,
                                              const float* __restrict__ O2,
                                              const float* __restrict__ Add, int C,
                                              u16* __restrict__ OutB)
{
    const int c = blockIdx.x * 256 + threadIdx.x;
    const int t0 = blockIdx.y * SEGLEN2;
    float acc = O2[(size_t)blockIdx.y * C + c];
    for (int t = t0; t < t0 + SEGLEN2; ++t) {
        float v = acc + (Add ? Add[(size_t)t * C + c] : 0.f);
        OutB[(size_t)t * C + c] = f2bf(v);
        acc += W[(size_t)t * C + c];
    }
}

// losses[t] = sum_n Xb[t,n]*(sum_z CpY[z]) + sum_c Ub[t,c]*(sum_z CpZ[z])
__global__ __launch_bounds__(256) void rowdot_part(
    const u16* __restrict__ Xb, const u16* __restrict__ CpY,
    const u16* __restrict__ Ub, const u16* __restrict__ CpZ,
    float* __restrict__ out)
{
    const int t = blockIdx.x;
    float s = 0.f;
    for (int n = threadIdx.x; n < N_; n += 256) {
        float y = 0.f;
        #pragma unroll
        for (int z = 0; z < 4; ++z)
            y += bf2f(CpY[(size_t)z * (T_ * N_) + (size_t)t * N_ + n]);
        s += bf2f(Xb[(size_t)t * N_ + n]) * y;
    }
    for (int c = threadIdx.x; c < MC_; c += 256) {
        float zz = 0.f;
        #pragma unroll
        for (int z = 0; z < 4; ++z)
            zz += bf2f(CpZ[(size_t)z * (T_ * MC_) + (size_t)t * MC_ + c]);
        s += bf2f(Ub[(size_t)t * MC_ + c]) * zz;
    }
    __shared__ float red[256];
    red[threadIdx.x] = s;
    __syncthreads();
    for (int off = 128; off > 0; off >>= 1) {
        if (threadIdx.x < off) red[threadIdx.x] += red[threadIdx.x + off];
        __syncthreads();
    }
    if (threadIdx.x == 0) out[t] = red[0];
}

// ---------------------------------------------------------------------------
extern "C" void kernel_launch(void* const* d_in, const int* in_sizes, int n_in,
                              void* d_out, int out_size, void* d_ws, size_t ws_size,
                              hipStream_t stream)
{
    const float* Qm   = (const float*)d_in[2];
    const float* Rm   = (const float*)d_in[3];
    const float* Km   = (const float*)d_in[4];
    const float* Em   = (const float*)d_in[5];
    const float* bias = (const float*)d_in[6];
    const float* Estu = (const float*)d_in[7];   // [J_, N_]
    const float* phi  = (const float*)d_in[8];   // [T, KF]
    const float* w    = (const float*)d_in[9];   // [T, N]
    float* out = (float*)d_out;

    // ---- workspace: 63 MB overlay region + ~44 MB persistent ≈ 107 MB
    char* w8 = (char*)d_ws;
    size_t off = 0;
    auto alloc = [&](size_t bytes) -> void* {
        void* p = w8 + off; off += (bytes + 255) & ~(size_t)255; return p;
    };
    char*  P     = (char*) alloc(62914560);                    // 63 MB overlay
    u16*   EstuB = (u16*)  alloc((size_t)KF_ * N_ * MC_ * 2);  // 21 MB
    float* D     = (float*)alloc((size_t)T_ * MC_ * 4);
    u16*   Ub0   = (u16*)  alloc((size_t)T_ * MC_ * 2);
    u16*   Ub    = (u16*)  alloc((size_t)T_ * MC_ * 2);
    float* V     = (float*)alloc((size_t)T_ * N_ * 4);         // 8 MB (W aliases)
    u16*   Xb    = (u16*)  alloc((size_t)T_ * N_ * 2);
    u16*   Qb    = (u16*)  alloc((size_t)N_ * N_ * 2);
    u16*   Rb    = (u16*)  alloc((size_t)MC_ * MC_ * 2);
    float* S2    = (float*)alloc((size_t)NSEG2 * N_ * 4);
    float* O2    = (float*)alloc((size_t)NSEG2 * N_ * 4);
    float* W     = V;                                          // [T, MC] alias

    // Overlays in P:
    // phase 1: Fb2(10.5M) | Eb(21M) | EbT(5.25M) | Kb(1M) | Wb(4.2M) | CpYwe(21M)
    // phase 2: Fb2 | CpNeu(42M @ +10.5M)    [Eb..CpYwe dead]
    // phase 3: CpX4(16.8M @ 0)              [Fb2 dead, CpNeu consumed]
    // phase 4: CpY(16.8M @ 0) | CpZ(8.4M @ +16.8M)
    u16*   Fb2   = (u16*)  P;
    u16*   Eb    = (u16*)  (P + 10485760);
    u16*   EbT   = (u16*)  (P + 31457280);
    u16*   Kb    = (u16*)  (P + 36700160);
    u16*   Wb    = (u16*)  (P + 37748736);
    u16*   CpYwe = (u16*)  (P + 41943040);
    u16*   CpNeu = (u16*)  (P + 10485760);
    u16*   CpX4  = (u16*)  P;
    u16*   CpY   = (u16*)  P;
    u16*   CpZ   = (u16*)  (P + 16777216);

    dim3 blk(256);

    // Phase 1: all casts in one launch + operand builders
    cast_all<<<dim3(14080), blk, 0, stream>>>(Km, Qm, Rm, w, Estu,
                                              Kb, Qb, Rb, Wb, Eb);
    build_EbT<<<dim3(MC_), blk, 0, stream>>>(Em, EbT);
    transpose_estub<<<dim3(J_ / 32, N_ / 32), blk, 0, stream>>>(Estu, EstuB);

    // F2[i][c'][c] = -sum_n K[c',n]*Estu[i,c,n]  (batched z=20, 320 blocks)
    gemm_tn<<<dim3(4, 4, KF_), blk, 0, stream>>>(
        Kb, Eb, nullptr, nullptr, nullptr, Fb2, MC_, MC_, N_, (long)MC_ * N_, -1.0f);

    // ywE partials (split-K z=2; 640 blocks) -> fused D build
    gemm_tn<<<dim3((MC_ * M_) / 128, T_ / 128, 2), blk, 0, stream>>>(
        Wb, EbT, nullptr, nullptr, nullptr, CpYwe, T_, MC_ * M_, N_, 0, 1.0f);
    build_D2<<<dim3(T_ * MC_ / 256), blk, 0, stream>>>(CpYwe, bias, D, Ub0);

    // Phase 2 — Neumann (prefix-commuted): partial_i = F_i u0; W = phi-reduce;
    // U1 = D + prefix(W)
    gemm_tn<<<dim3(4, 16, KF_), blk, 0, stream>>>(
        Ub0, Fb2, nullptr, nullptr, nullptr, CpNeu, T_, MC_, MC_, (long)MC_ * MC_, 1.0f);
    phired_scanS<<<dim3(MC_ / 256, NSEG2), blk, 0, stream>>>(CpNeu, phi, W, S2);
    scan2B<<<dim3(MC_ / 256), blk, 0, stream>>>(S2, MC_, O2);
    scan2C<<<dim3(MC_ / 256, NSEG2), blk, 0, stream>>>(W, O2, D, MC_, Ub);

    // Phase 3 — X: phi fused in GEMM epilogue (z=4 groups of 5; 512 blocks);
    // V = 4-way sum; X = prefix(V)
    gemm_phi<<<dim3(8, 16, 4), blk, 0, stream>>>(
        Ub, EstuB, phi, CpX4, T_, N_, (long)N_ * MC_, 5);
    sumred_scanS<<<dim3(N_ / 256, NSEG2), blk, 0, stream>>>(CpX4, V, S2);
    scan2B<<<dim3(N_ / 256), blk, 0, stream>>>(S2, N_, O2);
    scan2C<<<dim3(N_ / 256, NSEG2), blk, 0, stream>>>(V, O2, nullptr, N_, Xb);

    // Phase 4 — Y = X@Q, Z = U@R (split-K z=4 partials), fused loss dot
    gemm_tn<<<dim3(N_ / 128, T_ / 128, 4), blk, 0, stream>>>(
        Xb, Qb, nullptr, nullptr, nullptr, CpY, T_, N_, N_, 0, 1.0f);
    gemm_tn<<<dim3(MC_ / 128, T_ / 128, 4), blk, 0, stream>>>(
        Ub, Rb, nullptr, nullptr, nullptr, CpZ, T_, MC_, MC_, 0, 1.0f);
    rowdot_part<<<dim3(T_), blk, 0, stream>>>(Xb, CpY, Ub, CpZ, out);
}

// Round 13
// 227.665 us; speedup vs baseline: 1.4071x; 1.2262x over previous
//
#include <hip/hip_runtime.h>

// Problem constants (fixed by the reference)
#define T_    2048
#define N_    1024
#define MC_   512
#define KF_   20
#define M_    5
#define J_    (KF_ * MC_)      // 10240
#define NSEG2 64
#define SEGLEN2 (T_ / NSEG2)   // 32

typedef unsigned short u16;
typedef __attribute__((ext_vector_type(8))) __bf16 bf16v;          // MFMA A/B frag
typedef __attribute__((ext_vector_type(4))) float  f32x4;          // MFMA C/D frag
typedef __attribute__((ext_vector_type(8))) unsigned short u16x8;

__device__ inline u16 f2bf(float f) {                      // RNE f32 -> bf16
    unsigned u = __float_as_uint(f);
    u += 0x7fff + ((u >> 16) & 1);
    return (u16)(u >> 16);
}
__device__ inline float bf2f(u16 v) { return __uint_as_float((unsigned)v << 16); }

__device__ inline void gload16(const void* g, void* l) {   // 16B global -> LDS (lane*16 dest)
    __builtin_amdgcn_global_load_lds((const __attribute__((address_space(1))) void*)g,
                                     (__attribute__((address_space(3))) void*)l, 16, 0, 0);
}

// ---------------------------------------------------------------------------
// bf16 MFMA GEMM, TN form (r6/r10-proven core): 128x128 tile, BK=64, 4 waves,
// double-buffered LDS, stage-next-early, one __syncthreads per K-step.
// LDS swizzle: 16B chunk ch (0..7) in each 128B row XORed with (row&7) on the
// GLOBAL SOURCE (dest linear, rule #21) and on ds_read; conflict-free.
// strideB != 0 -> BATCH mode (bz indexes B and the Cp slot, full Kdim).
// strideB == 0 -> split-K over grid.z. Cp: bf16 per-bz output. else +Add,
// write Cf (f32) / Cb (bf16). XCD chunk-swizzled block ids (total%8==0).
// ---------------------------------------------------------------------------
__global__ __launch_bounds__(256) void gemm_tn(
    const u16* __restrict__ A, const u16* __restrict__ B,
    const float* __restrict__ Add, float* __restrict__ Cf,
    u16* __restrict__ Cb, u16* __restrict__ Cp,
    int Mdim, int Ndim, int Kdim, long strideB, float alpha)
{
    __shared__ u16 As[2][128 * 64];
    __shared__ u16 Bs[2][128 * 64];

    const int gx = gridDim.x, gy = gridDim.y;
    const int total = gx * gy * gridDim.z;
    int lin = blockIdx.x + gx * (blockIdx.y + gy * blockIdx.z);
    lin = (lin & 7) * (total >> 3) + (lin >> 3);
    int bx, by, bz;
    if (gx <= gy) { bx = lin % gx; int r = lin / gx; by = r % gy; bz = r / gy; }
    else          { by = lin % gy; int r = lin / gy; bx = r % gx; bz = r / gx; }

    if (strideB) B += (size_t)bz * strideB;
    const int Kc   = strideB ? Kdim : (Kdim / gridDim.z);
    const int kbeg = strideB ? 0 : bz * Kc;

    const int tid = threadIdx.x;
    const int wv = tid >> 6, ln = tid & 63;
    const int wr = wv >> 1, wc = wv & 1;
    const int l15 = ln & 15, l4 = ln >> 4;
    const int m0 = by * 128, n0 = bx * 128;
    const int nt = Kc / 64;

    f32x4 acc[4][4] = {};

    size_t arow[4], brow[4];
    int lbase[4];
    #pragma unroll
    for (int q = 0; q < 4; ++q) {
        const int c = q * 256 + tid;
        const int row = c >> 3, ch = c & 7;
        const int src = ((ch ^ (row & 7)) * 8);
        arow[q] = (size_t)(m0 + row) * Kdim + src;
        brow[q] = (size_t)(n0 + row) * Kdim + src;
        lbase[q] = (q * 256 + wv * 64) * 8;
    }
    const int fsw = l15 & 7;

    #pragma unroll
    for (int q = 0; q < 4; ++q) {
        gload16(A + arow[q] + kbeg, &As[0][lbase[q]]);
        gload16(B + brow[q] + kbeg, &Bs[0][lbase[q]]);
    }
    __syncthreads();

    int cur = 0;
    for (int t = 0; t < nt; ++t) {
        if (t + 1 < nt) {
            const int kk = kbeg + (t + 1) * 64;
            #pragma unroll
            for (int q = 0; q < 4; ++q) {
                gload16(A + arow[q] + kk, &As[cur ^ 1][lbase[q]]);
                gload16(B + brow[q] + kk, &Bs[cur ^ 1][lbase[q]]);
            }
        }
        bf16v a[4][2], b[4][2];
        #pragma unroll
        for (int i = 0; i < 4; ++i)
            #pragma unroll
            for (int s = 0; s < 2; ++s) {
                const int ch = ((s * 4 + l4) ^ fsw) * 8;
                a[i][s] = *(const bf16v*)&As[cur][(wr * 64 + i * 16 + l15) * 64 + ch];
                b[i][s] = *(const bf16v*)&Bs[cur][(wc * 64 + i * 16 + l15) * 64 + ch];
            }
        #pragma unroll
        for (int s = 0; s < 2; ++s)
            #pragma unroll
            for (int i = 0; i < 4; ++i)
                #pragma unroll
                for (int j = 0; j < 4; ++j)
                    acc[i][j] = __builtin_amdgcn_mfma_f32_16x16x32_bf16(
                        a[i][s], b[j][s], acc[i][j], 0, 0, 0);
        __syncthreads();
        cur ^= 1;
    }

    #pragma unroll
    for (int i = 0; i < 4; ++i)
        #pragma unroll
        for (int j = 0; j < 4; ++j)
            #pragma unroll
            for (int r = 0; r < 4; ++r) {
                const int gm = m0 + wr * 64 + i * 16 + l4 * 4 + r;
                const int gn = n0 + wc * 64 + j * 16 + l15;
                const size_t off = (size_t)gm * Ndim + gn;
                float v = alpha * acc[i][j][r];
                if (Cp) {
                    Cp[(size_t)bz * Mdim * Ndim + off] = f2bf(v);
                } else {
                    if (Add) v += Add[off];
                    if (Cf) Cf[off] = v;
                    if (Cb) Cb[off] = f2bf(v);
                }
            }
}

// ---------------------------------------------------------------------------
// gemm_phi: batched TN GEMM with phi-scale FUSED in the epilogue.
// Kdim MUST be 512 (8 K-steps). bz = batch GROUP of NB consecutive i; block
// loops its NB batches, accumulating accF += phi[row, i] * acc after each
// batch's K-loop. Partials: Cp[bz] (one per group). r6-proven inner loop.
// Used for BOTH the Neumann step (B = F2, Ndim=MC) and X (B = EstuB, Ndim=N).
// ---------------------------------------------------------------------------
__global__ __launch_bounds__(256, 2) void gemm_phi(
    const u16* __restrict__ A, const u16* __restrict__ B,
    const float* __restrict__ phi_, u16* __restrict__ Cp,
    int Mdim, int Ndim, long strideB, int NB)
{
    __shared__ u16 As[2][128 * 64];
    __shared__ u16 Bs[2][128 * 64];
    const int Kdim = 512;

    const int gx = gridDim.x, gy = gridDim.y;
    const int total = gx * gy * gridDim.z;
    int lin = blockIdx.x + gx * (blockIdx.y + gy * blockIdx.z);
    lin = (lin & 7) * (total >> 3) + (lin >> 3);
    int bx, by, bz;
    if (gx <= gy) { bx = lin % gx; int r = lin / gx; by = r % gy; bz = r / gy; }
    else          { by = lin % gy; int r = lin / gy; bx = r % gx; bz = r / gx; }

    const int tid = threadIdx.x;
    const int wv = tid >> 6, ln = tid & 63;
    const int wr = wv >> 1, wc = wv & 1;
    const int l15 = ln & 15, l4 = ln >> 4;
    const int m0 = by * 128, n0 = bx * 128;

    f32x4 acc[4][4] = {};
    f32x4 accF[4][4] = {};

    size_t arow[4], brow[4];
    int lbase[4];
    #pragma unroll
    for (int q = 0; q < 4; ++q) {
        const int c = q * 256 + tid;
        const int row = c >> 3, ch = c & 7;
        const int src = ((ch ^ (row & 7)) * 8);
        arow[q] = (size_t)(m0 + row) * Kdim + src;
        brow[q] = (size_t)(n0 + row) * Kdim + src;
        lbase[q] = (q * 256 + wv * 64) * 8;
    }
    const int fsw = l15 & 7;
    const int NT = NB * 8;

    auto stage = [&](int u, int bb) {
        const int qb = u >> 3, tt = u & 7;
        const u16* Bq = B + (size_t)(bz * NB + qb) * strideB;
        const int kk = tt * 64;
        #pragma unroll
        for (int q = 0; q < 4; ++q) {
            gload16(A + arow[q] + kk, &As[bb][lbase[q]]);
            gload16(Bq + brow[q] + kk, &Bs[bb][lbase[q]]);
        }
    };

    stage(0, 0);
    __syncthreads();

    int cur = 0;
    for (int u = 0; u < NT; ++u) {
        if (u + 1 < NT) stage(u + 1, cur ^ 1);
        bf16v a[4][2], b[4][2];
        #pragma unroll
        for (int i = 0; i < 4; ++i)
            #pragma unroll
            for (int s = 0; s < 2; ++s) {
                const int ch = ((s * 4 + l4) ^ fsw) * 8;
                a[i][s] = *(const bf16v*)&As[cur][(wr * 64 + i * 16 + l15) * 64 + ch];
                b[i][s] = *(const bf16v*)&Bs[cur][(wc * 64 + i * 16 + l15) * 64 + ch];
            }
        #pragma unroll
        for (int s = 0; s < 2; ++s)
            #pragma unroll
            for (int i = 0; i < 4; ++i)
                #pragma unroll
                for (int j = 0; j < 4; ++j)
                    acc[i][j] = __builtin_amdgcn_mfma_f32_16x16x32_bf16(
                        a[i][s], b[j][s], acc[i][j], 0, 0, 0);
        if ((u & 7) == 7) {                      // end of batch i: fold phi
            const int ig = bz * NB + (u >> 3);
            float ph[4][4];
            #pragma unroll
            for (int i = 0; i < 4; ++i)
                #pragma unroll
                for (int r = 0; r < 4; ++r)
                    ph[i][r] = phi_[(size_t)(m0 + wr * 64 + i * 16 + l4 * 4 + r) * KF_ + ig];
            #pragma unroll
            for (int i = 0; i < 4; ++i)
                #pragma unroll
                for (int j = 0; j < 4; ++j) {
                    #pragma unroll
                    for (int r = 0; r < 4; ++r)
                        accF[i][j][r] += ph[i][r] * acc[i][j][r];
                    acc[i][j] = (f32x4){0.f, 0.f, 0.f, 0.f};
                }
        }
        __syncthreads();
        cur ^= 1;
    }

    #pragma unroll
    for (int i = 0; i < 4; ++i)
        #pragma unroll
        for (int j = 0; j < 4; ++j)
            #pragma unroll
            for (int r = 0; r < 4; ++r) {
                const int gm = m0 + wr * 64 + i * 16 + l4 * 4 + r;
                const int gn = n0 + wc * 64 + j * 16 + l15;
                Cp[(size_t)bz * Mdim * Ndim + (size_t)gm * Ndim + gn] = f2bf(accF[i][j][r]);
            }
}

// All five f32->bf16 casts in one kernel (range-dispatched on float4 index)
__global__ __launch_bounds__(256) void cast_all(
    const float* __restrict__ Km, const float* __restrict__ Qm,
    const float* __restrict__ Rm, const float* __restrict__ w,
    const float* __restrict__ Estu,
    u16* __restrict__ Kb, u16* __restrict__ Qb, u16* __restrict__ Rb,
    u16* __restrict__ Wb, u16* __restrict__ Eb)
{
    const int g = blockIdx.x * 256 + threadIdx.x;   // float4 index, total 3604480
    const float* src; u16* dst; int base;
    if      (g <  131072) { src = Km;   dst = Kb; base = 0; }
    else if (g <  393216) { src = Qm;   dst = Qb; base = 131072; }
    else if (g <  458752) { src = Rm;   dst = Rb; base = 393216; }
    else if (g <  983040) { src = w;    dst = Wb; base = 458752; }
    else                  { src = Estu; dst = Eb; base = 983040; }
    const int i = g - base;
    float4 v = *(const float4*)(src + (size_t)i * 4);
    ushort4 o; o.x = f2bf(v.x); o.y = f2bf(v.y); o.z = f2bf(v.z); o.w = f2bf(v.w);
    *(ushort4*)(dst + (size_t)i * 4) = o;
}

// EstuB[(i*1024 + n)*512 + c] = Estu[(i*512 + c)*1024 + n], bf16
__global__ __launch_bounds__(256) void transpose_estub(const float* __restrict__ in,
                                                       u16* __restrict__ out)
{
    __shared__ float tile[32][33];
    const int j0 = blockIdx.x * 32, n0 = blockIdx.y * 32;
    const int tx = threadIdx.x & 31, ty = threadIdx.x >> 5;
    #pragma unroll
    for (int r = 0; r < 4; ++r)
        tile[ty + r * 8][tx] = in[(size_t)(j0 + ty + r * 8) * N_ + n0 + tx];
    __syncthreads();
    const int i = j0 >> 9, cbase = j0 & 511;
    #pragma unroll
    for (int r = 0; r < 4; ++r)
        out[((size_t)i * N_ + n0 + ty + r * 8) * MC_ + cbase + tx] =
            f2bf(tile[tx][ty + r * 8]);
}

// EbT[(c*5+ii)][n] = E[c][n][ii]  bf16
__global__ __launch_bounds__(256) void build_EbT(const float* __restrict__ E,
                                                 u16* __restrict__ EbT)
{
    const int c = blockIdx.x;
    for (int n = threadIdx.x; n < N_; n += 256) {
        const float* ep = E + (size_t)c * (N_ * M_) + (size_t)n * M_;
        #pragma unroll
        for (int ii = 0; ii < M_; ++ii)
            EbT[(size_t)(c * M_ + ii) * N_ + n] = f2bf(ep[ii]);
    }
}

// D[t,c] = bias[c] + sum_z sum_ii CpYwe[z][(t-4+ii)*2560 + c*5+ii]  (fused reduce)
__global__ __launch_bounds__(256) void build_D2(const u16* __restrict__ Cp,
                                                const float* __restrict__ bias,
                                                float* __restrict__ D,
                                                u16* __restrict__ Ub0)
{
    const int idx = blockIdx.x * 256 + threadIdx.x;
    const int t = idx >> 9, c = idx & 511;
    float v = bias[c];
    #pragma unroll
    for (int ii = 0; ii < M_; ++ii) {
        const int ts = t - (M_ - 1) + ii;
        if (ts >= 0) {
            v += bf2f(Cp[(size_t)ts * (MC_ * M_) + c * M_ + ii]);
            v += bf2f(Cp[(size_t)T_ * (MC_ * M_) + (size_t)ts * (MC_ * M_) + c * M_ + ii]);
        }
    }
    D[idx] = v;
    Ub0[idx] = f2bf(v);
}

// Vectorized 4-plane partial reduce + segment sums:
//   Vo[t,n] = sum_{z<4} Cp[z][t*C+n];  S2[seg][n] = sum_{t in seg} Vo[t,n]
// u16x8 loads (16B/lane); 4 t-rows in flight; LDS cross-reduce for S2.
// grid: (C/512, NSEG2), block 256: lane owns 8 consecutive n.
__global__ __launch_bounds__(256) void sumred_scanS(
    const u16* __restrict__ Cp, int C, float* __restrict__ Vo,
    float* __restrict__ S2)
{
    const int n8 = blockIdx.x * 512 + (threadIdx.x & 63) * 8;
    const int trow = threadIdx.x >> 6;              // 0..3
    const int t0 = blockIdx.y * SEGLEN2;
    float a[8] = {};
    for (int t = t0 + trow; t < t0 + SEGLEN2; t += 4) {
        float s[8] = {};
        #pragma unroll
        for (int z = 0; z < 4; ++z) {
            u16x8 v = *(const u16x8*)(Cp + (size_t)z * ((size_t)T_ * C) + (size_t)t * C + n8);
            #pragma unroll
            for (int k = 0; k < 8; ++k) s[k] += bf2f(v[k]);
        }
        *(float4*)(Vo + (size_t)t * C + n8)     = make_float4(s[0], s[1], s[2], s[3]);
        *(float4*)(Vo + (size_t)t * C + n8 + 4) = make_float4(s[4], s[5], s[6], s[7]);
        #pragma unroll
        for (int k = 0; k < 8; ++k) a[k] += s[k];
    }
    __shared__ float red[256][8];
    #pragma unroll
    for (int k = 0; k < 8; ++k) red[threadIdx.x][k] = a[k];
    __syncthreads();
    if (trow == 0) {
        #pragma unroll
        for (int k = 0; k < 8; ++k) {
            float v = red[threadIdx.x][k] + red[threadIdx.x + 64][k]
                    + red[threadIdx.x + 128][k] + red[threadIdx.x + 192][k];
            S2[(size_t)blockIdx.y * C + n8 + k] = v;
        }
    }
}

// Exclusive scan of NSEG2 segment sums per column
__global__ __launch_bounds__(256) void scan2B(const float* __restrict__ S2, int C,
                                              float* __restrict__ O2)
{
    const int c = blockIdx.x * 256 + threadIdx.x;
    float off = 0.f;
    #pragma unroll
    for (int s = 0; s < NSEG2; ++s) {
        O2[(size_t)s * C + c] = off;
        off += S2[(size_t)s * C + c];
    }
}

// OutB[t,c] = bf16( (Add? Add[t,c]:0) + strict-prefix(W)[t,c] )
__global__ __launch_bounds__(256) void scan2C(const float* __restrict__ W,
                                              const float* __restrict__ O2,
                                              const float* __restrict__ Add, int C,
                                              u16* __restrict__ OutB)
{
    const int c = blockIdx.x * 256 + threadIdx.x;
    const int t0 = blockIdx.y * SEGLEN2;
    float acc = O2[(size_t)blockIdx.y * C + c];
    for (int t = t0; t < t0 + SEGLEN2; ++t) {
        float v = acc + (Add ? Add[(size_t)t * C + c] : 0.f);
        OutB[(size_t)t * C + c] = f2bf(v);
        acc += W[(size_t)t * C + c];
    }
}

// losses[t] = sum_n Xb[t,n]*(sum_z CpY[z]) + sum_c Ub[t,c]*(sum_z CpZ[z])
__global__ __launch_bounds__(256) void rowdot_part(
    const u16* __restrict__ Xb, const u16* __restrict__ CpY,
    const u16* __restrict__ Ub, const u16* __restrict__ CpZ,
    float* __restrict__ out)
{
    const int t = blockIdx.x;
    float s = 0.f;
    for (int n = threadIdx.x; n < N_; n += 256) {
        float y = 0.f;
        #pragma unroll
        for (int z = 0; z < 4; ++z)
            y += bf2f(CpY[(size_t)z * (T_ * N_) + (size_t)t * N_ + n]);
        s += bf2f(Xb[(size_t)t * N_ + n]) * y;
    }
    for (int c = threadIdx.x; c < MC_; c += 256) {
        float zz = 0.f;
        #pragma unroll
        for (int z = 0; z < 4; ++z)
            zz += bf2f(CpZ[(size_t)z * (T_ * MC_) + (size_t)t * MC_ + c]);
        s += bf2f(Ub[(size_t)t * MC_ + c]) * zz;
    }
    __shared__ float red[256];
    red[threadIdx.x] = s;
    __syncthreads();
    for (int off = 128; off > 0; off >>= 1) {
        if (threadIdx.x < off) red[threadIdx.x] += red[threadIdx.x + off];
        __syncthreads();
    }
    if (threadIdx.x == 0) out[t] = red[0];
}

// ---------------------------------------------------------------------------
extern "C" void kernel_launch(void* const* d_in, const int* in_sizes, int n_in,
                              void* d_out, int out_size, void* d_ws, size_t ws_size,
                              hipStream_t stream)
{
    const float* Qm   = (const float*)d_in[2];
    const float* Rm   = (const float*)d_in[3];
    const float* Km   = (const float*)d_in[4];
    const float* Em   = (const float*)d_in[5];
    const float* bias = (const float*)d_in[6];
    const float* Estu = (const float*)d_in[7];   // [J_, N_]
    const float* phi  = (const float*)d_in[8];   // [T, KF]
    const float* w    = (const float*)d_in[9];   // [T, N]
    float* out = (float*)d_out;

    // ---- workspace: 63 MB overlay region + ~44 MB persistent ≈ 107 MB
    char* w8 = (char*)d_ws;
    size_t off = 0;
    auto alloc = [&](size_t bytes) -> void* {
        void* p = w8 + off; off += (bytes + 255) & ~(size_t)255; return p;
    };
    char*  P     = (char*) alloc(62914560);                    // 63 MB overlay
    u16*   EstuB = (u16*)  alloc((size_t)KF_ * N_ * MC_ * 2);  // 21 MB
    float* D     = (float*)alloc((size_t)T_ * MC_ * 4);
    u16*   Ub0   = (u16*)  alloc((size_t)T_ * MC_ * 2);
    u16*   Ub    = (u16*)  alloc((size_t)T_ * MC_ * 2);
    float* V     = (float*)alloc((size_t)T_ * N_ * 4);         // 8 MB (W aliases)
    u16*   Xb    = (u16*)  alloc((size_t)T_ * N_ * 2);
    u16*   Qb    = (u16*)  alloc((size_t)N_ * N_ * 2);
    u16*   Rb    = (u16*)  alloc((size_t)MC_ * MC_ * 2);
    float* S2    = (float*)alloc((size_t)NSEG2 * N_ * 4);
    float* O2    = (float*)alloc((size_t)NSEG2 * N_ * 4);
    float* W     = V;                                          // [T, MC] alias

    // Overlays in P:
    // phase 1: Fb2(10.5M) | Eb(21M) | EbT(5.25M) | Kb(1M) | Wb(4.2M) | CpYwe(21M)
    // phase 2: Fb2 | CpNeu4(8.4M @ +10.5M)   [Eb..CpYwe dead]
    // phase 3: CpX4(16.8M @ 0)               [Fb2 dead, CpNeu4 consumed]
    // phase 4: CpY(16.8M @ 0) | CpZ(8.4M @ +16.8M)
    u16*   Fb2    = (u16*)  P;
    u16*   Eb     = (u16*)  (P + 10485760);
    u16*   EbT    = (u16*)  (P + 31457280);
    u16*   Kb     = (u16*)  (P + 36700160);
    u16*   Wb     = (u16*)  (P + 37748736);
    u16*   CpYwe  = (u16*)  (P + 41943040);
    u16*   CpNeu4 = (u16*)  (P + 10485760);
    u16*   CpX4   = (u16*)  P;
    u16*   CpY    = (u16*)  P;
    u16*   CpZ    = (u16*)  (P + 16777216);

    dim3 blk(256);

    // Phase 1: all casts in one launch + operand builders
    cast_all<<<dim3(14080), blk, 0, stream>>>(Km, Qm, Rm, w, Estu,
                                              Kb, Qb, Rb, Wb, Eb);
    build_EbT<<<dim3(MC_), blk, 0, stream>>>(Em, EbT);
    transpose_estub<<<dim3(J_ / 32, N_ / 32), blk, 0, stream>>>(Estu, EstuB);

    // F2[i][c'][c] = -sum_n K[c',n]*Estu[i,c,n]  (batched z=20, 320 blocks)
    gemm_tn<<<dim3(4, 4, KF_), blk, 0, stream>>>(
        Kb, Eb, nullptr, nullptr, nullptr, Fb2, MC_, MC_, N_, (long)MC_ * N_, -1.0f);

    // ywE partials (split-K z=2; 640 blocks) -> fused D build
    gemm_tn<<<dim3((MC_ * M_) / 128, T_ / 128, 2), blk, 0, stream>>>(
        Wb, EbT, nullptr, nullptr, nullptr, CpYwe, T_, MC_ * M_, N_, 0, 1.0f);
    build_D2<<<dim3(T_ * MC_ / 256), blk, 0, stream>>>(CpYwe, bias, D, Ub0);

    // Phase 2 — Neumann, phi fused in GEMM epilogue (z=4 groups of 5; 256 blocks):
    // CpNeu4[z][t,c'] = sum_{i in group z} phi[t,i]*(F_i u0_t)[c'];
    // W = 4-way sum; U1 = D + prefix(W)
    gemm_phi<<<dim3(4, 16, 4), blk, 0, stream>>>(
        Ub0, Fb2, phi, CpNeu4, T_, MC_, (long)MC_ * MC_, 5);
    sumred_scanS<<<dim3(MC_ / 512, NSEG2), blk, 0, stream>>>(CpNeu4, MC_, W, S2);
    scan2B<<<dim3(MC_ / 256), blk, 0, stream>>>(S2, MC_, O2);
    scan2C<<<dim3(MC_ / 256, NSEG2), blk, 0, stream>>>(W, O2, D, MC_, Ub);

    // Phase 3 — X: phi fused in GEMM epilogue (z=4 groups of 5; 512 blocks);
    // V = 4-way sum; X = prefix(V)
    gemm_phi<<<dim3(8, 16, 4), blk, 0, stream>>>(
        Ub, EstuB, phi, CpX4, T_, N_, (long)N_ * MC_, 5);
    sumred_scanS<<<dim3(N_ / 512, NSEG2), blk, 0, stream>>>(CpX4, N_, V, S2);
    scan2B<<<dim3(N_ / 256), blk, 0, stream>>>(S2, N_, O2);
    scan2C<<<dim3(N_ / 256, NSEG2), blk, 0, stream>>>(V, O2, nullptr, N_, Xb);

    // Phase 4 — Y = X@Q, Z = U@R (split-K z=4 partials), fused loss dot
    gemm_tn<<<dim3(N_ / 128, T_ / 128, 4), blk, 0, stream>>>(
        Xb, Qb, nullptr, nullptr, nullptr, CpY, T_, N_, N_, 0, 1.0f);
    gemm_tn<<<dim3(MC_ / 128, T_ / 128, 4), blk, 0, stream>>>(
        Ub, Rb, nullptr, nullptr, nullptr, CpZ, T_, MC_, MC_, 0, 1.0f);
    rowdot_part<<<dim3(T_), blk, 0, stream>>>(Xb, CpY, Ub, CpZ, out);
}

// Round 14
// 224.317 us; speedup vs baseline: 1.4281x; 1.0149x over previous
//
#include <hip/hip_runtime.h>

// Problem constants (fixed by the reference)
#define T_    2048
#define N_    1024
#define MC_   512
#define KF_   20
#define M_    5
#define J_    (KF_ * MC_)      // 10240
#define NSEG2 64
#define SEGLEN2 (T_ / NSEG2)   // 32

typedef unsigned short u16;
typedef __attribute__((ext_vector_type(8))) __bf16 bf16v;          // MFMA A/B frag
typedef __attribute__((ext_vector_type(4))) float  f32x4;          // MFMA C/D frag
typedef __attribute__((ext_vector_type(8))) unsigned short u16x8;

__device__ inline u16 f2bf(float f) {                      // RNE f32 -> bf16
    unsigned u = __float_as_uint(f);
    u += 0x7fff + ((u >> 16) & 1);
    return (u16)(u >> 16);
}
__device__ inline float bf2f(u16 v) { return __uint_as_float((unsigned)v << 16); }

__device__ inline void gload16(const void* g, void* l) {   // 16B global -> LDS (lane*16 dest)
    __builtin_amdgcn_global_load_lds((const __attribute__((address_space(1))) void*)g,
                                     (__attribute__((address_space(3))) void*)l, 16, 0, 0);
}

// ---------------------------------------------------------------------------
// bf16 MFMA GEMM, TN form (r6/r10-proven core): 128x128 tile, BK=64, 4 waves,
// double-buffered LDS, stage-next-early, one __syncthreads per K-step.
// LDS swizzle: 16B chunk ch (0..7) in each 128B row XORed with (row&7) on the
// GLOBAL SOURCE (dest linear, rule #21) and on ds_read; conflict-free.
// strideB != 0 -> BATCH mode (bz indexes B and the Cp slot, full Kdim).
// strideB == 0 -> split-K over grid.z. Cp: bf16 per-bz output. else +Add,
// write Cf (f32) / Cb (bf16). XCD chunk-swizzled block ids (total%8==0).
// ---------------------------------------------------------------------------
__global__ __launch_bounds__(256) void gemm_tn(
    const u16* __restrict__ A, const u16* __restrict__ B,
    const float* __restrict__ Add, float* __restrict__ Cf,
    u16* __restrict__ Cb, u16* __restrict__ Cp,
    int Mdim, int Ndim, int Kdim, long strideB, float alpha)
{
    __shared__ u16 As[2][128 * 64];
    __shared__ u16 Bs[2][128 * 64];

    const int gx = gridDim.x, gy = gridDim.y;
    const int total = gx * gy * gridDim.z;
    int lin = blockIdx.x + gx * (blockIdx.y + gy * blockIdx.z);
    lin = (lin & 7) * (total >> 3) + (lin >> 3);
    int bx, by, bz;
    if (gx <= gy) { bx = lin % gx; int r = lin / gx; by = r % gy; bz = r / gy; }
    else          { by = lin % gy; int r = lin / gy; bx = r % gx; bz = r / gx; }

    if (strideB) B += (size_t)bz * strideB;
    const int Kc   = strideB ? Kdim : (Kdim / gridDim.z);
    const int kbeg = strideB ? 0 : bz * Kc;

    const int tid = threadIdx.x;
    const int wv = tid >> 6, ln = tid & 63;
    const int wr = wv >> 1, wc = wv & 1;
    const int l15 = ln & 15, l4 = ln >> 4;
    const int m0 = by * 128, n0 = bx * 128;
    const int nt = Kc / 64;

    f32x4 acc[4][4] = {};

    size_t arow[4], brow[4];
    int lbase[4];
    #pragma unroll
    for (int q = 0; q < 4; ++q) {
        const int c = q * 256 + tid;
        const int row = c >> 3, ch = c & 7;
        const int src = ((ch ^ (row & 7)) * 8);
        arow[q] = (size_t)(m0 + row) * Kdim + src;
        brow[q] = (size_t)(n0 + row) * Kdim + src;
        lbase[q] = (q * 256 + wv * 64) * 8;
    }
    const int fsw = l15 & 7;

    #pragma unroll
    for (int q = 0; q < 4; ++q) {
        gload16(A + arow[q] + kbeg, &As[0][lbase[q]]);
        gload16(B + brow[q] + kbeg, &Bs[0][lbase[q]]);
    }
    __syncthreads();

    int cur = 0;
    for (int t = 0; t < nt; ++t) {
        if (t + 1 < nt) {
            const int kk = kbeg + (t + 1) * 64;
            #pragma unroll
            for (int q = 0; q < 4; ++q) {
                gload16(A + arow[q] + kk, &As[cur ^ 1][lbase[q]]);
                gload16(B + brow[q] + kk, &Bs[cur ^ 1][lbase[q]]);
            }
        }
        bf16v a[4][2], b[4][2];
        #pragma unroll
        for (int i = 0; i < 4; ++i)
            #pragma unroll
            for (int s = 0; s < 2; ++s) {
                const int ch = ((s * 4 + l4) ^ fsw) * 8;
                a[i][s] = *(const bf16v*)&As[cur][(wr * 64 + i * 16 + l15) * 64 + ch];
                b[i][s] = *(const bf16v*)&Bs[cur][(wc * 64 + i * 16 + l15) * 64 + ch];
            }
        #pragma unroll
        for (int s = 0; s < 2; ++s)
            #pragma unroll
            for (int i = 0; i < 4; ++i)
                #pragma unroll
                for (int j = 0; j < 4; ++j)
                    acc[i][j] = __builtin_amdgcn_mfma_f32_16x16x32_bf16(
                        a[i][s], b[j][s], acc[i][j], 0, 0, 0);
        __syncthreads();
        cur ^= 1;
    }

    #pragma unroll
    for (int i = 0; i < 4; ++i)
        #pragma unroll
        for (int j = 0; j < 4; ++j)
            #pragma unroll
            for (int r = 0; r < 4; ++r) {
                const int gm = m0 + wr * 64 + i * 16 + l4 * 4 + r;
                const int gn = n0 + wc * 64 + j * 16 + l15;
                const size_t off = (size_t)gm * Ndim + gn;
                float v = alpha * acc[i][j][r];
                if (Cp) {
                    Cp[(size_t)bz * Mdim * Ndim + off] = f2bf(v);
                } else {
                    if (Add) v += Add[off];
                    if (Cf) Cf[off] = v;
                    if (Cb) Cb[off] = f2bf(v);
                }
            }
}

// ---------------------------------------------------------------------------
// gemm_phi: batched TN GEMM with phi-scale FUSED in the epilogue.
// Kdim MUST be 512 (8 K-steps). bz = batch GROUP of NB consecutive i; block
// loops its NB batches, accumulating accF += phi[row, i] * acc after each
// batch's K-loop. Partials: Cp[bz] (one per group). r6-proven inner loop.
// Neumann: z=10 groups of 2 (640 blocks, 2/CU).  X: z=4 groups of 5 (512).
// ---------------------------------------------------------------------------
__global__ __launch_bounds__(256, 2) void gemm_phi(
    const u16* __restrict__ A, const u16* __restrict__ B,
    const float* __restrict__ phi_, u16* __restrict__ Cp,
    int Mdim, int Ndim, long strideB, int NB)
{
    __shared__ u16 As[2][128 * 64];
    __shared__ u16 Bs[2][128 * 64];
    const int Kdim = 512;

    const int gx = gridDim.x, gy = gridDim.y;
    const int total = gx * gy * gridDim.z;
    int lin = blockIdx.x + gx * (blockIdx.y + gy * blockIdx.z);
    lin = (lin & 7) * (total >> 3) + (lin >> 3);
    int bx, by, bz;
    if (gx <= gy) { bx = lin % gx; int r = lin / gx; by = r % gy; bz = r / gy; }
    else          { by = lin % gy; int r = lin / gy; bx = r % gx; bz = r / gx; }

    const int tid = threadIdx.x;
    const int wv = tid >> 6, ln = tid & 63;
    const int wr = wv >> 1, wc = wv & 1;
    const int l15 = ln & 15, l4 = ln >> 4;
    const int m0 = by * 128, n0 = bx * 128;

    f32x4 acc[4][4] = {};
    f32x4 accF[4][4] = {};

    size_t arow[4], brow[4];
    int lbase[4];
    #pragma unroll
    for (int q = 0; q < 4; ++q) {
        const int c = q * 256 + tid;
        const int row = c >> 3, ch = c & 7;
        const int src = ((ch ^ (row & 7)) * 8);
        arow[q] = (size_t)(m0 + row) * Kdim + src;
        brow[q] = (size_t)(n0 + row) * Kdim + src;
        lbase[q] = (q * 256 + wv * 64) * 8;
    }
    const int fsw = l15 & 7;
    const int NT = NB * 8;

    auto stage = [&](int u, int bb) {
        const int qb = u >> 3, tt = u & 7;
        const u16* Bq = B + (size_t)(bz * NB + qb) * strideB;
        const int kk = tt * 64;
        #pragma unroll
        for (int q = 0; q < 4; ++q) {
            gload16(A + arow[q] + kk, &As[bb][lbase[q]]);
            gload16(Bq + brow[q] + kk, &Bs[bb][lbase[q]]);
        }
    };

    stage(0, 0);
    __syncthreads();

    int cur = 0;
    for (int u = 0; u < NT; ++u) {
        if (u + 1 < NT) stage(u + 1, cur ^ 1);
        bf16v a[4][2], b[4][2];
        #pragma unroll
        for (int i = 0; i < 4; ++i)
            #pragma unroll
            for (int s = 0; s < 2; ++s) {
                const int ch = ((s * 4 + l4) ^ fsw) * 8;
                a[i][s] = *(const bf16v*)&As[cur][(wr * 64 + i * 16 + l15) * 64 + ch];
                b[i][s] = *(const bf16v*)&Bs[cur][(wc * 64 + i * 16 + l15) * 64 + ch];
            }
        #pragma unroll
        for (int s = 0; s < 2; ++s)
            #pragma unroll
            for (int i = 0; i < 4; ++i)
                #pragma unroll
                for (int j = 0; j < 4; ++j)
                    acc[i][j] = __builtin_amdgcn_mfma_f32_16x16x32_bf16(
                        a[i][s], b[j][s], acc[i][j], 0, 0, 0);
        if ((u & 7) == 7) {                      // end of batch i: fold phi
            const int ig = bz * NB + (u >> 3);
            float ph[4][4];
            #pragma unroll
            for (int i = 0; i < 4; ++i)
                #pragma unroll
                for (int r = 0; r < 4; ++r)
                    ph[i][r] = phi_[(size_t)(m0 + wr * 64 + i * 16 + l4 * 4 + r) * KF_ + ig];
            #pragma unroll
            for (int i = 0; i < 4; ++i)
                #pragma unroll
                for (int j = 0; j < 4; ++j) {
                    #pragma unroll
                    for (int r = 0; r < 4; ++r)
                        accF[i][j][r] += ph[i][r] * acc[i][j][r];
                    acc[i][j] = (f32x4){0.f, 0.f, 0.f, 0.f};
                }
        }
        __syncthreads();
        cur ^= 1;
    }

    #pragma unroll
    for (int i = 0; i < 4; ++i)
        #pragma unroll
        for (int j = 0; j < 4; ++j)
            #pragma unroll
            for (int r = 0; r < 4; ++r) {
                const int gm = m0 + wr * 64 + i * 16 + l4 * 4 + r;
                const int gn = n0 + wc * 64 + j * 16 + l15;
                Cp[(size_t)bz * Mdim * Ndim + (size_t)gm * Ndim + gn] = f2bf(accF[i][j][r]);
            }
}

// Four f32->bf16 casts in one kernel (range-dispatched on float4 index)
// (Estu handled by transpose_estub, which writes both orientations)
__global__ __launch_bounds__(256) void cast_all(
    const float* __restrict__ Km, const float* __restrict__ Qm,
    const float* __restrict__ Rm, const float* __restrict__ w,
    u16* __restrict__ Kb, u16* __restrict__ Qb, u16* __restrict__ Rb,
    u16* __restrict__ Wb)
{
    const int g = blockIdx.x * 256 + threadIdx.x;   // float4 index, total 983040
    const float* src; u16* dst; int base;
    if      (g <  131072) { src = Km;   dst = Kb; base = 0; }
    else if (g <  393216) { src = Qm;   dst = Qb; base = 131072; }
    else if (g <  458752) { src = Rm;   dst = Rb; base = 393216; }
    else                  { src = w;    dst = Wb; base = 458752; }
    const int i = g - base;
    float4 v = *(const float4*)(src + (size_t)i * 4);
    ushort4 o; o.x = f2bf(v.x); o.y = f2bf(v.y); o.z = f2bf(v.z); o.w = f2bf(v.w);
    *(ushort4*)(dst + (size_t)i * 4) = o;
}

// Reads Estu f32 ONCE; writes Eb (straight bf16 [J,N]) and
// EstuB[(i*1024+n)*512+c] = Estu[(i*512+c)*1024+n] (transposed bf16)
__global__ __launch_bounds__(256) void transpose_estub(const float* __restrict__ in,
                                                       u16* __restrict__ Eb,
                                                       u16* __restrict__ EstuB)
{
    __shared__ float tile[32][33];
    const int j0 = blockIdx.x * 32, n0 = blockIdx.y * 32;
    const int tx = threadIdx.x & 31, ty = threadIdx.x >> 5;
    #pragma unroll
    for (int r = 0; r < 4; ++r) {
        const size_t idx = (size_t)(j0 + ty + r * 8) * N_ + n0 + tx;
        float v = in[idx];
        Eb[idx] = f2bf(v);
        tile[ty + r * 8][tx] = v;
    }
    __syncthreads();
    const int i = j0 >> 9, cbase = j0 & 511;
    #pragma unroll
    for (int r = 0; r < 4; ++r)
        EstuB[((size_t)i * N_ + n0 + ty + r * 8) * MC_ + cbase + tx] =
            f2bf(tile[tx][ty + r * 8]);
}

// EbT[(c*5+ii)][n] = E[c][n][ii]  bf16 — vectorized via LDS row stage
__global__ __launch_bounds__(256) void build_EbT(const float* __restrict__ E,
                                                 u16* __restrict__ EbT)
{
    __shared__ float lds[N_ * M_];                // 20 KB
    const int c = blockIdx.x;
    const float* src = E + (size_t)c * (N_ * M_);
    for (int q = threadIdx.x; q < (N_ * M_) / 4; q += 256)
        *(float4*)&lds[q * 4] = *(const float4*)(src + (size_t)q * 4);
    __syncthreads();
    for (int n = threadIdx.x; n < N_; n += 256) {
        #pragma unroll
        for (int ii = 0; ii < M_; ++ii)
            EbT[(size_t)(c * M_ + ii) * N_ + n] = f2bf(lds[n * M_ + ii]);
    }
}

// D[t,c] = bias[c] + sum_z sum_ii CpYwe[z][(t-4+ii)*2560 + c*5+ii]  (fused reduce)
__global__ __launch_bounds__(256) void build_D2(const u16* __restrict__ Cp,
                                                const float* __restrict__ bias,
                                                float* __restrict__ D,
                                                u16* __restrict__ Ub0)
{
    const int idx = blockIdx.x * 256 + threadIdx.x;
    const int t = idx >> 9, c = idx & 511;
    float v = bias[c];
    #pragma unroll
    for (int ii = 0; ii < M_; ++ii) {
        const int ts = t - (M_ - 1) + ii;
        if (ts >= 0) {
            v += bf2f(Cp[(size_t)ts * (MC_ * M_) + c * M_ + ii]);
            v += bf2f(Cp[(size_t)T_ * (MC_ * M_) + (size_t)ts * (MC_ * M_) + c * M_ + ii]);
        }
    }
    D[idx] = v;
    Ub0[idx] = f2bf(v);
}

// Vectorized NZ-plane partial reduce + segment sums:
//   Vo[t,n] = sum_{z<NZ} Cp[z][t*C+n];  S2[seg][n] = sum_{t in seg} Vo[t,n]
template<int NZ>
__global__ __launch_bounds__(256) void sumred_scanS(
    const u16* __restrict__ Cp, int C, float* __restrict__ Vo,
    float* __restrict__ S2)
{
    const int n8 = blockIdx.x * 512 + (threadIdx.x & 63) * 8;
    const int trow = threadIdx.x >> 6;              // 0..3
    const int t0 = blockIdx.y * SEGLEN2;
    float a[8] = {};
    for (int t = t0 + trow; t < t0 + SEGLEN2; t += 4) {
        float s[8] = {};
        #pragma unroll
        for (int z = 0; z < NZ; ++z) {
            u16x8 v = *(const u16x8*)(Cp + (size_t)z * ((size_t)T_ * C) + (size_t)t * C + n8);
            #pragma unroll
            for (int k = 0; k < 8; ++k) s[k] += bf2f(v[k]);
        }
        *(float4*)(Vo + (size_t)t * C + n8)     = make_float4(s[0], s[1], s[2], s[3]);
        *(float4*)(Vo + (size_t)t * C + n8 + 4) = make_float4(s[4], s[5], s[6], s[7]);
        #pragma unroll
        for (int k = 0; k < 8; ++k) a[k] += s[k];
    }
    __shared__ float red[256][8];
    #pragma unroll
    for (int k = 0; k < 8; ++k) red[threadIdx.x][k] = a[k];
    __syncthreads();
    if (trow == 0) {
        #pragma unroll
        for (int k = 0; k < 8; ++k) {
            float v = red[threadIdx.x][k] + red[threadIdx.x + 64][k]
                    + red[threadIdx.x + 128][k] + red[threadIdx.x + 192][k];
            S2[(size_t)blockIdx.y * C + n8 + k] = v;
        }
    }
}

// Exclusive scan of NSEG2 segment sums per column
__global__ __launch_bounds__(256) void scan2B(const float* __restrict__ S2, int C,
                                              float* __restrict__ O2)
{
    const int c = blockIdx.x * 256 + threadIdx.x;
    float off = 0.f;
    #pragma unroll
    for (int s = 0; s < NSEG2; ++s) {
        O2[(size_t)s * C + c] = off;
        off += S2[(size_t)s * C + c];
    }
}

// OutB[t,c] = bf16( (Add? Add[t,c]:0) + strict-prefix(W)[t,c] )
__global__ __launch_bounds__(256) void scan2C(const float* __restrict__ W,
                                              const float* __restrict__ O2,
                                              const float* __restrict__ Add, int C,
                                              u16* __restrict__ OutB)
{
    const int c = blockIdx.x * 256 + threadIdx.x;
    const int t0 = blockIdx.y * SEGLEN2;
    float acc = O2[(size_t)blockIdx.y * C + c];
    for (int t = t0; t < t0 + SEGLEN2; ++t) {
        float v = acc + (Add ? Add[(size_t)t * C + c] : 0.f);
        OutB[(size_t)t * C + c] = f2bf(v);
        acc += W[(size_t)t * C + c];
    }
}

// losses[t] = sum_n Xb[t,n]*(sum_z CpY[z]) + sum_c Ub[t,c]*(sum_z CpZ[z])
__global__ __launch_bounds__(256) void rowdot_part(
    const u16* __restrict__ Xb, const u16* __restrict__ CpY,
    const u16* __restrict__ Ub, const u16* __restrict__ CpZ,
    float* __restrict__ out)
{
    const int t = blockIdx.x;
    float s = 0.f;
    for (int n = threadIdx.x; n < N_; n += 256) {
        float y = 0.f;
        #pragma unroll
        for (int z = 0; z < 4; ++z)
            y += bf2f(CpY[(size_t)z * (T_ * N_) + (size_t)t * N_ + n]);
        s += bf2f(Xb[(size_t)t * N_ + n]) * y;
    }
    for (int c = threadIdx.x; c < MC_; c += 256) {
        float zz = 0.f;
        #pragma unroll
        for (int z = 0; z < 4; ++z)
            zz += bf2f(CpZ[(size_t)z * (T_ * MC_) + (size_t)t * MC_ + c]);
        s += bf2f(Ub[(size_t)t * MC_ + c]) * zz;
    }
    __shared__ float red[256];
    red[threadIdx.x] = s;
    __syncthreads();
    for (int off = 128; off > 0; off >>= 1) {
        if (threadIdx.x < off) red[threadIdx.x] += red[threadIdx.x + off];
        __syncthreads();
    }
    if (threadIdx.x == 0) out[t] = red[0];
}

// ---------------------------------------------------------------------------
extern "C" void kernel_launch(void* const* d_in, const int* in_sizes, int n_in,
                              void* d_out, int out_size, void* d_ws, size_t ws_size,
                              hipStream_t stream)
{
    const float* Qm   = (const float*)d_in[2];
    const float* Rm   = (const float*)d_in[3];
    const float* Km   = (const float*)d_in[4];
    const float* Em   = (const float*)d_in[5];
    const float* bias = (const float*)d_in[6];
    const float* Estu = (const float*)d_in[7];   // [J_, N_]
    const float* phi  = (const float*)d_in[8];   // [T, KF]
    const float* w    = (const float*)d_in[9];   // [T, N]
    float* out = (float*)d_out;

    // ---- workspace: 63 MB overlay region + ~44 MB persistent ≈ 107 MB
    char* w8 = (char*)d_ws;
    size_t off = 0;
    auto alloc = [&](size_t bytes) -> void* {
        void* p = w8 + off; off += (bytes + 255) & ~(size_t)255; return p;
    };
    char*  P     = (char*) alloc(62914560);                    // 63 MB overlay
    u16*   EstuB = (u16*)  alloc((size_t)KF_ * N_ * MC_ * 2);  // 21 MB
    float* D     = (float*)alloc((size_t)T_ * MC_ * 4);
    u16*   Ub0   = (u16*)  alloc((size_t)T_ * MC_ * 2);
    u16*   Ub    = (u16*)  alloc((size_t)T_ * MC_ * 2);
    float* V     = (float*)alloc((size_t)T_ * N_ * 4);         // 8 MB (W aliases)
    u16*   Xb    = (u16*)  alloc((size_t)T_ * N_ * 2);
    u16*   Qb    = (u16*)  alloc((size_t)N_ * N_ * 2);
    u16*   Rb    = (u16*)  alloc((size_t)MC_ * MC_ * 2);
    float* S2    = (float*)alloc((size_t)NSEG2 * N_ * 4);
    float* O2    = (float*)alloc((size_t)NSEG2 * N_ * 4);
    float* W     = V;                                          // [T, MC] alias

    // Overlays in P:
    // phase 1: Fb2(10.5M) | Eb(21M) | EbT(5.25M) | Kb(1M) | Wb(4.2M) | CpYwe(21M)
    // phase 2: Fb2 | CpNeu10(20M @ +10.5M, ends exactly at EbT)  [Eb dead]
    // phase 3: CpX4(16.8M @ 0)               [Fb2 dead, CpNeu10 consumed]
    // phase 4: CpY(16.8M @ 0) | CpZ(8.4M @ +16.8M)
    u16*   Fb2     = (u16*)  P;
    u16*   Eb      = (u16*)  (P + 10485760);
    u16*   EbT     = (u16*)  (P + 31457280);
    u16*   Kb      = (u16*)  (P + 36700160);
    u16*   Wb      = (u16*)  (P + 37748736);
    u16*   CpYwe   = (u16*)  (P + 41943040);
    u16*   CpNeu10 = (u16*)  (P + 10485760);
    u16*   CpX4    = (u16*)  P;
    u16*   CpY     = (u16*)  P;
    u16*   CpZ     = (u16*)  (P + 16777216);

    dim3 blk(256);

    // Phase 1: casts + operand builders (Estu read once in transpose_estub)
    cast_all<<<dim3(3840), blk, 0, stream>>>(Km, Qm, Rm, w, Kb, Qb, Rb, Wb);
    transpose_estub<<<dim3(J_ / 32, N_ / 32), blk, 0, stream>>>(Estu, Eb, EstuB);
    build_EbT<<<dim3(MC_), blk, 0, stream>>>(Em, EbT);

    // F2[i][c'][c] = -sum_n K[c',n]*Estu[i,c,n]  (batched z=20, 320 blocks)
    gemm_tn<<<dim3(4, 4, KF_), blk, 0, stream>>>(
        Kb, Eb, nullptr, nullptr, nullptr, Fb2, MC_, MC_, N_, (long)MC_ * N_, -1.0f);

    // ywE partials (split-K z=2; 640 blocks) -> fused D build
    gemm_tn<<<dim3((MC_ * M_) / 128, T_ / 128, 2), blk, 0, stream>>>(
        Wb, EbT, nullptr, nullptr, nullptr, CpYwe, T_, MC_ * M_, N_, 0, 1.0f);
    build_D2<<<dim3(T_ * MC_ / 256), blk, 0, stream>>>(CpYwe, bias, D, Ub0);

    // Phase 2 — Neumann, phi fused in GEMM epilogue (z=10 groups of 2; 640
    // blocks = 2/CU): CpNeu10[z][t,c'] = sum_{i in grp z} phi[t,i]*(F_i u0_t)[c'];
    // W = 10-way sum; U1 = D + prefix(W)
    gemm_phi<<<dim3(4, 16, 10), blk, 0, stream>>>(
        Ub0, Fb2, phi, CpNeu10, T_, MC_, (long)MC_ * MC_, 2);
    sumred_scanS<10><<<dim3(MC_ / 512, NSEG2), blk, 0, stream>>>(CpNeu10, MC_, W, S2);
    scan2B<<<dim3(MC_ / 256), blk, 0, stream>>>(S2, MC_, O2);
    scan2C<<<dim3(MC_ / 256, NSEG2), blk, 0, stream>>>(W, O2, D, MC_, Ub);

    // Phase 3 — X: phi fused in GEMM epilogue (z=4 groups of 5; 512 blocks);
    // V = 4-way sum; X = prefix(V)
    gemm_phi<<<dim3(8, 16, 4), blk, 0, stream>>>(
        Ub, EstuB, phi, CpX4, T_, N_, (long)N_ * MC_, 5);
    sumred_scanS<4><<<dim3(N_ / 512, NSEG2), blk, 0, stream>>>(CpX4, N_, V, S2);
    scan2B<<<dim3(N_ / 256), blk, 0, stream>>>(S2, N_, O2);
    scan2C<<<dim3(N_ / 256, NSEG2), blk, 0, stream>>>(V, O2, nullptr, N_, Xb);

    // Phase 4 — Y = X@Q, Z = U@R (split-K z=4 partials), fused loss dot
    gemm_tn<<<dim3(N_ / 128, T_ / 128, 4), blk, 0, stream>>>(
        Xb, Qb, nullptr, nullptr, nullptr, CpY, T_, N_, N_, 0, 1.0f);
    gemm_tn<<<dim3(MC_ / 128, T_ / 128, 4), blk, 0, stream>>>(
        Ub, Rb, nullptr, nullptr, nullptr, CpZ, T_, MC_, MC_, 0, 1.0f);
    rowdot_part<<<dim3(T_), blk, 0, stream>>>(Xb, CpY, Ub, CpZ, out);
}